// Round 15
// baseline (128.631 us; speedup 1.0000x reference)
//
#include <hip/hip_runtime.h>
#include <math.h>

#define N_DIM 1024
#define G_DIM 4096
#define B_DIM 2048
#define K2DIM 2048  // 2*N (real|imag concatenated K)

typedef __attribute__((ext_vector_type(8))) short bf16x8;
typedef __attribute__((ext_vector_type(8))) unsigned short u16x8;
typedef __attribute__((ext_vector_type(16))) float f32x16;
typedef unsigned short ushort_t;

// ---------- ws layout (bytes) ----------
#define WS_PRBF  0u                      // bf16 [G][1024]   8 MB
#define WS_PIBF  (8u << 20)              // bf16 [G][1024]   8 MB
#define WS_HBF   (16u << 20)             // bf16 [B][2048]   8 MB ([Hr | -Hi])
#define WS_WG    (24u << 20)             // int [B]
#define WS_WXR   (WS_WG + 8192u)         // f32 [B]
#define WS_WXI   (WS_WXR + 8192u)        // f32 [B]

__device__ __forceinline__ unsigned short f2bf(float f) {
  unsigned u = __float_as_uint(f);
  unsigned r = u + 0x7fffu + ((u >> 16) & 1u);
  return (unsigned short)(r >> 16);
}
__device__ __forceinline__ float bf2f(unsigned short u) {
  return __uint_as_float(((unsigned)u) << 16);
}
__device__ __forceinline__ bf16x8 negbf(bf16x8 v) {
  union { bf16x8 b; uint4 u; } x;
  x.b = v;
  x.u.x ^= 0x80008000u; x.u.y ^= 0x80008000u;
  x.u.z ^= 0x80008000u; x.u.w ^= 0x80008000u;
  return x.b;
}
// fast tanh via v_exp_f32 (alpha in [0,1) -> no overflow concerns)
__device__ __forceinline__ float tanh_fast(float x) {
  const float t = __expf(2.0f * x);
  return __fdividef(t - 1.0f, t + 1.0f);
}

__device__ __forceinline__ void gload_lds16(const void* gsrc, void* ldst) {
  __builtin_amdgcn_global_load_lds(
      (const __attribute__((address_space(1))) void*)gsrc,
      (__attribute__((address_space(3))) void*)ldst, 16, 0, 0);
}

// ---------- K1: fused PSI generation + H conversion (fully vectorized) ------
__global__ __launch_bounds__(256) void k_prep(
    const float* __restrict__ theta, const float* __restrict__ alpha,
    const float* __restrict__ H,
    float* __restrict__ prT, float* __restrict__ piT,
    ushort_t* __restrict__ prBf, ushort_t* __restrict__ piBf,
    ushort_t* __restrict__ hbf) {
  __shared__ float sp[32][33], si[32][33];
  const int bid = blockIdx.x, tid = threadIdx.x;
  if (bid < 4096) {
    // PSI: 32n x 32g tile; float4 reads, one pass (8 thr/row x 32 rows)
    const int g0 = (bid & 127) * 32, n0 = (bid >> 7) * 32;
    const int c4 = (tid & 7) * 4, row = tid >> 3;
    const size_t idx = (size_t)(n0 + row) * G_DIM + g0 + c4;
    const float4 a4 = *reinterpret_cast<const float4*>(alpha + idx);
    const float4 t4 = *reinterpret_cast<const float4*>(theta + idx);
#pragma unroll
    for (int j = 0; j < 4; ++j) {
      const float av = (j == 0) ? a4.x : (j == 1) ? a4.y : (j == 2) ? a4.z : a4.w;
      const float tv = (j == 0) ? t4.x : (j == 1) ? t4.y : (j == 2) ? t4.z : t4.w;
      const float a = tanh_fast(av) * 0.03125f;  // 1/sqrt(1024)
      sp[row][c4 + j] = a * __cosf(tv);
      si[row][c4 + j] = a * __sinf(tv);
    }
    __syncthreads();
    // write: g = g0 + grow, n-quad = n0 + c4; float4 / ushort4 stores
    const int grow = row;
    const size_t obase = (size_t)(g0 + grow) * N_DIM + n0 + c4;
    float4 vr, vi;
    ushort4 ur, ui;
#pragma unroll
    for (int j = 0; j < 4; ++j) {
      const float pr = sp[c4 + j][grow], pi = si[c4 + j][grow];
      if (j == 0) { vr.x = pr; vi.x = pi; ur.x = f2bf(pr); ui.x = f2bf(pi); }
      else if (j == 1) { vr.y = pr; vi.y = pi; ur.y = f2bf(pr); ui.y = f2bf(pi); }
      else if (j == 2) { vr.z = pr; vi.z = pi; ur.z = f2bf(pr); ui.z = f2bf(pi); }
      else { vr.w = pr; vi.w = pi; ur.w = f2bf(pr); ui.w = f2bf(pi); }
    }
    *reinterpret_cast<float4*>(prT + obase) = vr;
    *reinterpret_cast<float4*>(piT + obase) = vi;
    *reinterpret_cast<ushort4*>(prBf + obase) = ur;
    *reinterpret_cast<ushort4*>(piBf + obase) = ui;
  } else {
    // H -> bf16, layout [B][2048] = [Hr | -Hi]
    const int j4 = ((bid - 4096) * 256 + tid) * 4;
    const int b = j4 >> 11, k = j4 & 2047, c = k >> 10, n = k & 1023;
    float4 v = *reinterpret_cast<const float4*>(
        H + (size_t)c * (B_DIM * N_DIM) + (size_t)b * N_DIM + n);
    if (c) { v.x = -v.x; v.y = -v.y; v.z = -v.z; v.w = -v.w; }
    ushort4 u;
    u.x = f2bf(v.x); u.y = f2bf(v.y); u.z = f2bf(v.z); u.w = f2bf(v.w);
    *reinterpret_cast<ushort4*>(hbf + j4) = u;
  }
}

#define LGKM(n) asm volatile("s_waitcnt lgkmcnt(" #n ")" ::: "memory")
#define SB0() __builtin_amdgcn_sched_barrier(0)

// ---------- K2: merged-B 32x32x16 dual-acc GEMM -> |x|^2 (bf16) ----------
// Best-measured core (62.8us): BM=256, BN=128, merged 32 k-lo + 32 k-hi.
// 8 waves 4M x 2N. LDS 2-ring x 48KB = 96KB; slot ^= row&7.
// accr = aL*pr + aH*pi ; acci = aL*pi + aH*(-pr)   (aH = -Hi)
__global__ __launch_bounds__(512, 2) void k_gemm(
    const ushort_t* __restrict__ hbf, const ushort_t* __restrict__ prBf,
    const ushort_t* __restrict__ piBf, ushort_t* __restrict__ xabsBf) {
  __shared__ ushort_t smem[49152];     // 96 KB: 2 bufs x 24576 ushorts
  const int tid = threadIdx.x;
  const int l = tid & 63, w = tid >> 6;
  const int wm = w >> 1, wn = w & 1;   // 4M x 2N
  const int bid = blockIdx.x;
  const int xcd = bid & 7, idx = bid >> 3;
  const int g0 = (xcd * 4 + (idx & 3)) * 128;
  const int b0 = (idx >> 2) * 256;

  // fragment offsets: rows 64 ushorts (128 B), slot ^= row&7 (row&7 == l&7)
  const int h = l >> 5;
  int colL[2], colH[2];
#pragma unroll
  for (int ks = 0; ks < 2; ++ks) {
    colL[ks] = ((ks * 2 + h) ^ (l & 7)) * 8;
    colH[ks] = ((4 + ks * 2 + h) ^ (l & 7)) * 8;
  }
  int rowA[2], rowB[2];
#pragma unroll
  for (int mi = 0; mi < 2; ++mi) rowA[mi] = (wm * 64 + mi * 32 + (l & 31)) * 64;
#pragma unroll
  for (int ni = 0; ni < 2; ++ni) rowB[ni] = 16384 + (wn * 64 + ni * 32 + (l & 31)) * 64;

  // staging: linear LDS dest, inverse-swizzled global source
  const int rT = tid >> 3, sd = tid & 7, sl = sd ^ (rT & 7);
  const ushort_t* srcA = hbf + (sl < 4 ? sl * 8 : 1024 + (sl - 4) * 8);
  const ushort_t* srcB = (sl < 4) ? (prBf + sl * 8) : (piBf + (sl - 4) * 8);
  const int dBase = (tid & ~63) * 8;

  f32x16 accr[2][2], acci[2][2];
#pragma unroll
  for (int mi = 0; mi < 2; ++mi)
#pragma unroll
    for (int ni = 0; ni < 2; ++ni) {
      accr[mi][ni] = (f32x16)(0.f);
      acci[mi][ni] = (f32x16)(0.f);
    }

  // prologue: stage tile 0 into buf 0
#pragma unroll
  for (int i = 0; i < 4; ++i)
    gload_lds16(srcA + (size_t)(b0 + i * 64 + rT) * K2DIM, (void*)(smem + i * 4096 + dBase));
#pragma unroll
  for (int i = 0; i < 2; ++i)
    gload_lds16(srcB + (size_t)(g0 + i * 64 + rT) * N_DIM, (void*)(smem + 16384 + i * 4096 + dBase));
  asm volatile("s_waitcnt vmcnt(0)" ::: "memory");
  __builtin_amdgcn_s_barrier();

  bf16x8 aL[2][2], aH[2][2], prB[2][2], piB[2][2], prN[2][2];

  // pre-read aL + prB of tile 0 (8 reads outstanding entering the loop)
  {
    const ushort_t* buf = smem;
#pragma unroll
    for (int mi = 0; mi < 2; ++mi)
#pragma unroll
      for (int ks = 0; ks < 2; ++ks)
        aL[mi][ks] = *(const bf16x8*)&buf[rowA[mi] + colL[ks]];
#pragma unroll
    for (int ni = 0; ni < 2; ++ni)
#pragma unroll
      for (int ks = 0; ks < 2; ++ks)
        prB[ni][ks] = *(const bf16x8*)&buf[rowB[ni] + colL[ks]];
  }

  for (int t = 0; t < 32; ++t) {
    const ushort_t* buf = smem + (t & 1) * 24576;
    const int nb = ((t + 1) & 1) * 24576;
    const int kp = (t + 1) * 32;
    const bool pf = (t < 31);

    // ---- P0: read piB; stage A(0,1); S0: accr += aL*pr
#pragma unroll
    for (int ni = 0; ni < 2; ++ni)
#pragma unroll
      for (int ks = 0; ks < 2; ++ks)
        piB[ni][ks] = *(const bf16x8*)&buf[rowB[ni] + colH[ks]];
    if (pf) {
#pragma unroll
      for (int i = 0; i < 2; ++i)
        gload_lds16(srcA + (size_t)(b0 + i * 64 + rT) * K2DIM + kp,
                    (void*)(smem + nb + i * 4096 + dBase));
    }
    LGKM(4); SB0();
    __builtin_amdgcn_s_setprio(1);
#pragma unroll
    for (int mi = 0; mi < 2; ++mi)
#pragma unroll
      for (int ni = 0; ni < 2; ++ni)
#pragma unroll
        for (int ks = 0; ks < 2; ++ks)
          accr[mi][ni] = __builtin_amdgcn_mfma_f32_32x32x16_bf16(aL[mi][ks], prB[ni][ks], accr[mi][ni], 0, 0, 0);
    __builtin_amdgcn_s_setprio(0);

    // ---- P1: read aH; stage A(2,3) + B(0,1); S1: acci += aL*pi
#pragma unroll
    for (int mi = 0; mi < 2; ++mi)
#pragma unroll
      for (int ks = 0; ks < 2; ++ks)
        aH[mi][ks] = *(const bf16x8*)&buf[rowA[mi] + colH[ks]];
    if (pf) {
#pragma unroll
      for (int i = 0; i < 2; ++i)
        gload_lds16(srcA + (size_t)(b0 + (i + 2) * 64 + rT) * K2DIM + kp,
                    (void*)(smem + nb + (i + 2) * 4096 + dBase));
#pragma unroll
      for (int i = 0; i < 2; ++i)
        gload_lds16(srcB + (size_t)(g0 + i * 64 + rT) * N_DIM + kp,
                    (void*)(smem + nb + 16384 + i * 4096 + dBase));
    }
    LGKM(4); SB0();
    __builtin_amdgcn_s_setprio(1);
#pragma unroll
    for (int mi = 0; mi < 2; ++mi)
#pragma unroll
      for (int ni = 0; ni < 2; ++ni)
#pragma unroll
        for (int ks = 0; ks < 2; ++ks)
          acci[mi][ni] = __builtin_amdgcn_mfma_f32_32x32x16_bf16(aL[mi][ks], piB[ni][ks], acci[mi][ni], 0, 0, 0);
    __builtin_amdgcn_s_setprio(0);

    // ---- P2: prN = -prB; S2: accr += aH*pi
#pragma unroll
    for (int ni = 0; ni < 2; ++ni)
#pragma unroll
      for (int ks = 0; ks < 2; ++ks)
        prN[ni][ks] = negbf(prB[ni][ks]);
    LGKM(0); SB0();
    __builtin_amdgcn_s_setprio(1);
#pragma unroll
    for (int mi = 0; mi < 2; ++mi)
#pragma unroll
      for (int ni = 0; ni < 2; ++ni)
#pragma unroll
        for (int ks = 0; ks < 2; ++ks)
          accr[mi][ni] = __builtin_amdgcn_mfma_f32_32x32x16_bf16(aH[mi][ks], piB[ni][ks], accr[mi][ni], 0, 0, 0);
    __builtin_amdgcn_s_setprio(0);

    // ---- P3: tile boundary; pre-read next aL+prB; S3: acci += aH*(-pr)
    if (pf) {
      asm volatile("s_waitcnt vmcnt(0)" ::: "memory");
      __builtin_amdgcn_s_barrier();
      const ushort_t* bn = smem + nb;
#pragma unroll
      for (int mi = 0; mi < 2; ++mi)
#pragma unroll
        for (int ks = 0; ks < 2; ++ks)
          aL[mi][ks] = *(const bf16x8*)&bn[rowA[mi] + colL[ks]];
#pragma unroll
      for (int ni = 0; ni < 2; ++ni)
#pragma unroll
        for (int ks = 0; ks < 2; ++ks)
          prB[ni][ks] = *(const bf16x8*)&bn[rowB[ni] + colL[ks]];
      SB0();
    }
    __builtin_amdgcn_s_setprio(1);
#pragma unroll
    for (int mi = 0; mi < 2; ++mi)
#pragma unroll
      for (int ni = 0; ni < 2; ++ni)
#pragma unroll
        for (int ks = 0; ks < 2; ++ks)
          acci[mi][ni] = __builtin_amdgcn_mfma_f32_32x32x16_bf16(aH[mi][ks], prN[ni][ks], acci[mi][ni], 0, 0, 0);
    __builtin_amdgcn_s_setprio(0);
  }

  // epilogue: |x|^2 as bf16. C/D: col=l&31, row=(reg&3)+8*(reg>>2)+4*(l>>5)
  const int rb0 = wm * 64 + 4 * (l >> 5);
#pragma unroll
  for (int mi = 0; mi < 2; ++mi)
#pragma unroll
    for (int ni = 0; ni < 2; ++ni) {
      const int gcol = g0 + wn * 64 + ni * 32 + (l & 31);
      const f32x16 r = accr[mi][ni], q = acci[mi][ni];
#pragma unroll
      for (int reg = 0; reg < 16; ++reg) {
        const int row = rb0 + mi * 32 + (reg & 3) + 8 * (reg >> 2);
        xabsBf[(size_t)(b0 + row) * G_DIM + gcol] = f2bf(r[reg] * r[reg] + q[reg] * q[reg]);
      }
    }
}

// ---------- K3: fused row-max + candidate scan + fp64 refine -> winner ----
__global__ __launch_bounds__(256) void k_scanrefine(
    const ushort_t* __restrict__ xb, const float* __restrict__ H,
    const float* __restrict__ prT, const float* __restrict__ piT,
    int* __restrict__ wg, float* __restrict__ wxr, float* __restrict__ wxi) {
  __shared__ float red[4];
  __shared__ int scnt;
  __shared__ int scand[64];
  __shared__ double dred[8];
  const int b = blockIdx.x, tid = threadIdx.x;
  const int l = tid & 63, w = tid >> 6;
  // scan phase: bf16 row (8KB), block max, candidates within 0.25 margin
  const ushort_t* row = xb + (size_t)b * G_DIM + tid * 16;
  const u16x8 u0 = *(const u16x8*)row;
  const u16x8 u1 = *(const u16x8*)(row + 8);
  float v[16];
#pragma unroll
  for (int j = 0; j < 8; ++j) { v[j] = bf2f(u0[j]); v[8 + j] = bf2f(u1[j]); }
  float m = v[0];
#pragma unroll
  for (int j = 1; j < 16; ++j) m = fmaxf(m, v[j]);
#pragma unroll
  for (int off = 32; off; off >>= 1) m = fmaxf(m, __shfl_xor(m, off));
  if (tid == 0) scnt = 0;
  if (l == 0) red[w] = m;
  __syncthreads();
  const float thr = fmaxf(fmaxf(red[0], red[1]), fmaxf(red[2], red[3])) - 0.25f;
#pragma unroll
  for (int j = 0; j < 16; ++j)
    if (v[j] >= thr) { int p = atomicAdd(&scnt, 1); if (p < 64) scand[p] = tid * 16 + j; }
  __syncthreads();
  int cnt = scnt;
  if (cnt > 64) cnt = 64;
  // refine phase: fp64 dot per candidate
  double best = -1.0, bxr = 0.0, bxi = 0.0;
  int bg = 0;
  for (int ci = 0; ci < cnt; ++ci) {
    const int g = scand[ci];
    double xr = 0.0, xi = 0.0;
    for (int n = tid; n < N_DIM; n += 256) {
      const double hr = H[(size_t)b * N_DIM + n];
      const double hi = H[(size_t)B_DIM * N_DIM + (size_t)b * N_DIM + n];
      const double pr = prT[(size_t)g * N_DIM + n];
      const double pi = piT[(size_t)g * N_DIM + n];
      xr += hr * pr - hi * pi;
      xi += hr * pi + hi * pr;
    }
    for (int off = 32; off; off >>= 1) {
      xr += __shfl_down(xr, off);
      xi += __shfl_down(xi, off);
    }
    if (l == 0) { dred[w * 2] = xr; dred[w * 2 + 1] = xi; }
    __syncthreads();
    if (tid == 0) {
      const double sxr = dred[0] + dred[2] + dred[4] + dred[6];
      const double sxi = dred[1] + dred[3] + dred[5] + dred[7];
      const double xab = sxr * sxr + sxi * sxi;
      if (xab > best || (xab == best && g < bg)) { best = xab; bg = g; bxr = sxr; bxi = sxi; }
    }
    __syncthreads();
  }
  if (tid == 0) { wg[b] = bg; wxr[b] = (float)bxr; wxi[b] = (float)bxi; }
}

// ---------- K4: y = winner x conj(PSI col) + zero both x planes + scatter ----
__global__ void k_y(const ushort_t* __restrict__ prBf, const ushort_t* __restrict__ piBf,
                    const int* __restrict__ wg, const float* __restrict__ wxr,
                    const float* __restrict__ wxi, float* __restrict__ out) {
  const int b = blockIdx.x, tid = threadIdx.x;
  const int g = wg[b];
  const float xr = wxr[b], xi = wxi[b];
  float* yr = out + (size_t)2 * B_DIM * G_DIM + (size_t)b * N_DIM;
  float* yi = yr + (size_t)B_DIM * N_DIM;
  const int n0 = tid * 4;
  const ushort4 p4 = *reinterpret_cast<const ushort4*>(prBf + (size_t)g * N_DIM + n0);
  const ushort4 q4 = *reinterpret_cast<const ushort4*>(piBf + (size_t)g * N_DIM + n0);
  float4 vr, vi;
  { const float pr = bf2f(p4.x), pi = bf2f(q4.x); vr.x = xr * pr + xi * pi; vi.x = xi * pr - xr * pi; }
  { const float pr = bf2f(p4.y), pi = bf2f(q4.y); vr.y = xr * pr + xi * pi; vi.y = xi * pr - xr * pi; }
  { const float pr = bf2f(p4.z), pi = bf2f(q4.z); vr.z = xr * pr + xi * pi; vi.z = xi * pr - xr * pi; }
  { const float pr = bf2f(p4.w), pi = bf2f(q4.w); vr.w = xr * pr + xi * pi; vi.w = xi * pr - xr * pi; }
  *reinterpret_cast<float4*>(yr + n0) = vr;
  *reinterpret_cast<float4*>(yi + n0) = vi;
  // zero BOTH x-plane rows b (real plane held prT/piT scratch; imag untouched)
  const float4 z = {0.f, 0.f, 0.f, 0.f};
  float* zr = out + (size_t)b * G_DIM + tid * 16;
  float* zi = out + (size_t)B_DIM * G_DIM + (size_t)b * G_DIM + tid * 16;
#pragma unroll
  for (int j = 0; j < 4; ++j) {
    *reinterpret_cast<float4*>(zr + j * 4) = z;
    *reinterpret_cast<float4*>(zi + j * 4) = z;
  }
  __syncthreads();
  if (tid == 0) {
    out[(size_t)b * G_DIM + g] = xr;                           // x real
    out[(size_t)B_DIM * G_DIM + (size_t)b * G_DIM + g] = xi;   // x imag
  }
}

extern "C" void kernel_launch(void* const* d_in, const int* in_sizes, int n_in,
                              void* d_out, int out_size, void* d_ws, size_t ws_size,
                              hipStream_t stream) {
  const float* H = (const float*)d_in[0];
  const float* theta = (const float*)d_in[1];
  const float* alpha = (const float*)d_in[2];
  float* out = (float*)d_out;
  char* ws = (char*)d_ws;

  ushort_t* prBf = (ushort_t*)(ws + WS_PRBF);
  ushort_t* piBf = (ushort_t*)(ws + WS_PIBF);
  ushort_t* hbf = (ushort_t*)(ws + WS_HBF);
  int* wg = (int*)(ws + WS_WG);
  float* wxr = (float*)(ws + WS_WXR);
  float* wxi = (float*)(ws + WS_WXI);

  // d_out scratch: real x-plane holds prT/piT; y-region holds bf16 xabs
  float* prT = out;                          // [G][N] f32 (16 MB)
  float* piT = out + 4194304;                // [G][N] f32 (16 MB)
  ushort_t* xabsBf = (ushort_t*)(out + 16777216);  // y-region scratch (16 MB)

  k_prep<<<8192, 256, 0, stream>>>(theta, alpha, H, prT, piT, prBf, piBf, hbf);
  k_gemm<<<256, 512, 0, stream>>>(hbf, prBf, piBf, xabsBf);
  k_scanrefine<<<B_DIM, 256, 0, stream>>>(xabsBf, H, prT, piT, wg, wxr, wxi);
  k_y<<<B_DIM, 256, 0, stream>>>(prBf, piBf, wg, wxr, wxi, out);  // y + zero + scatter
}

// Round 16
// 122.492 us; speedup vs baseline: 1.0501x; 1.0501x over previous
//
#include <hip/hip_runtime.h>
#include <math.h>

#define N_DIM 1024
#define G_DIM 4096
#define B_DIM 2048
#define K2DIM 2048  // 2*N (real|imag concatenated K)

typedef __attribute__((ext_vector_type(8))) short bf16x8;
typedef __attribute__((ext_vector_type(8))) unsigned short u16x8;
typedef __attribute__((ext_vector_type(16))) float f32x16;
typedef unsigned short ushort_t;

// ---------- ws layout (bytes) ----------
#define WS_PRBF  0u                      // bf16 [G][1024]   8 MB
#define WS_PIBF  (8u << 20)              // bf16 [G][1024]   8 MB
#define WS_HBF   (16u << 20)             // bf16 [B][2048]   8 MB ([Hr | -Hi])
#define WS_XABS  (24u << 20)             // bf16 [B][G]     16 MB
#define WS_WG    (40u << 20)             // int [B]
#define WS_WXR   (WS_WG + 8192u)         // f32 [B]
#define WS_WXI   (WS_WXR + 8192u)        // f32 [B]

__device__ __forceinline__ unsigned short f2bf(float f) {
  unsigned u = __float_as_uint(f);
  unsigned r = u + 0x7fffu + ((u >> 16) & 1u);
  return (unsigned short)(r >> 16);
}
__device__ __forceinline__ float bf2f(unsigned short u) {
  return __uint_as_float(((unsigned)u) << 16);
}
__device__ __forceinline__ bf16x8 negbf(bf16x8 v) {
  union { bf16x8 b; uint4 u; } x;
  x.b = v;
  x.u.x ^= 0x80008000u; x.u.y ^= 0x80008000u;
  x.u.z ^= 0x80008000u; x.u.w ^= 0x80008000u;
  return x.b;
}
// fast tanh via v_exp_f32 (alpha in [0,1) -> no overflow concerns)
__device__ __forceinline__ float tanh_fast(float x) {
  const float t = __expf(2.0f * x);
  return __fdividef(t - 1.0f, t + 1.0f);
}

__device__ __forceinline__ void gload_lds16(const void* gsrc, void* ldst) {
  __builtin_amdgcn_global_load_lds(
      (const __attribute__((address_space(1))) void*)gsrc,
      (__attribute__((address_space(3))) void*)ldst, 16, 0, 0);
}

// ---------- K1: fused PSI generation + H conversion (vectorized) ------
__global__ __launch_bounds__(256) void k_prep(
    const float* __restrict__ theta, const float* __restrict__ alpha,
    const float* __restrict__ H,
    float* __restrict__ prT, float* __restrict__ piT,
    ushort_t* __restrict__ prBf, ushort_t* __restrict__ piBf,
    ushort_t* __restrict__ hbf) {
  __shared__ float sp[32][33], si[32][33];
  const int bid = blockIdx.x, tid = threadIdx.x;
  if (bid < 4096) {
    // PSI: 32n x 32g tile; float4 reads, one pass (8 thr/row x 32 rows)
    const int g0 = (bid & 127) * 32, n0 = (bid >> 7) * 32;
    const int c4 = (tid & 7) * 4, row = tid >> 3;
    const size_t idx = (size_t)(n0 + row) * G_DIM + g0 + c4;
    const float4 a4 = *reinterpret_cast<const float4*>(alpha + idx);
    const float4 t4 = *reinterpret_cast<const float4*>(theta + idx);
#pragma unroll
    for (int j = 0; j < 4; ++j) {
      const float av = (j == 0) ? a4.x : (j == 1) ? a4.y : (j == 2) ? a4.z : a4.w;
      const float tv = (j == 0) ? t4.x : (j == 1) ? t4.y : (j == 2) ? t4.z : t4.w;
      const float a = tanh_fast(av) * 0.03125f;  // 1/sqrt(1024)
      sp[row][c4 + j] = a * __cosf(tv);
      si[row][c4 + j] = a * __sinf(tv);
    }
    __syncthreads();
    // write: g = g0 + row, n-quad = n0 + c4; float4 / ushort4 stores
    const size_t obase = (size_t)(g0 + row) * N_DIM + n0 + c4;
    float4 vr, vi;
    ushort4 ur, ui;
#pragma unroll
    for (int j = 0; j < 4; ++j) {
      const float pr = sp[c4 + j][row], pi = si[c4 + j][row];
      if (j == 0) { vr.x = pr; vi.x = pi; ur.x = f2bf(pr); ui.x = f2bf(pi); }
      else if (j == 1) { vr.y = pr; vi.y = pi; ur.y = f2bf(pr); ui.y = f2bf(pi); }
      else if (j == 2) { vr.z = pr; vi.z = pi; ur.z = f2bf(pr); ui.z = f2bf(pi); }
      else { vr.w = pr; vi.w = pi; ur.w = f2bf(pr); ui.w = f2bf(pi); }
    }
    *reinterpret_cast<float4*>(prT + obase) = vr;
    *reinterpret_cast<float4*>(piT + obase) = vi;
    *reinterpret_cast<ushort4*>(prBf + obase) = ur;
    *reinterpret_cast<ushort4*>(piBf + obase) = ui;
  } else {
    // H -> bf16, layout [B][2048] = [Hr | -Hi]
    const int j4 = ((bid - 4096) * 256 + tid) * 4;
    const int b = j4 >> 11, k = j4 & 2047, c = k >> 10, n = k & 1023;
    float4 v = *reinterpret_cast<const float4*>(
        H + (size_t)c * (B_DIM * N_DIM) + (size_t)b * N_DIM + n);
    if (c) { v.x = -v.x; v.y = -v.y; v.z = -v.z; v.w = -v.w; }
    ushort4 u;
    u.x = f2bf(v.x); u.y = f2bf(v.y); u.z = f2bf(v.z); u.w = f2bf(v.w);
    *reinterpret_cast<ushort4*>(hbf + j4) = u;
  }
}

#define LGKM(n) asm volatile("s_waitcnt lgkmcnt(" #n ")" ::: "memory")
#define SB0() __builtin_amdgcn_sched_barrier(0)

// ---------- K2: merged-B 32x32x16 dual-acc GEMM -> |x|^2 (bf16) ----------
// Best-measured core (62.8us): BM=256, BN=128, merged 32 k-lo + 32 k-hi.
// 8 waves 4M x 2N. LDS 2-ring x 48KB = 96KB; slot ^= row&7.
// accr = aL*pr + aH*pi ; acci = aL*pi + aH*(-pr)   (aH = -Hi)
__global__ __launch_bounds__(512, 2) void k_gemm(
    const ushort_t* __restrict__ hbf, const ushort_t* __restrict__ prBf,
    const ushort_t* __restrict__ piBf, ushort_t* __restrict__ xabsBf) {
  __shared__ ushort_t smem[49152];     // 96 KB: 2 bufs x 24576 ushorts
  const int tid = threadIdx.x;
  const int l = tid & 63, w = tid >> 6;
  const int wm = w >> 1, wn = w & 1;   // 4M x 2N
  const int bid = blockIdx.x;
  const int xcd = bid & 7, idx = bid >> 3;
  const int g0 = (xcd * 4 + (idx & 3)) * 128;
  const int b0 = (idx >> 2) * 256;

  // fragment offsets: rows 64 ushorts (128 B), slot ^= row&7 (row&7 == l&7)
  const int h = l >> 5;
  int colL[2], colH[2];
#pragma unroll
  for (int ks = 0; ks < 2; ++ks) {
    colL[ks] = ((ks * 2 + h) ^ (l & 7)) * 8;
    colH[ks] = ((4 + ks * 2 + h) ^ (l & 7)) * 8;
  }
  int rowA[2], rowB[2];
#pragma unroll
  for (int mi = 0; mi < 2; ++mi) rowA[mi] = (wm * 64 + mi * 32 + (l & 31)) * 64;
#pragma unroll
  for (int ni = 0; ni < 2; ++ni) rowB[ni] = 16384 + (wn * 64 + ni * 32 + (l & 31)) * 64;

  // staging: linear LDS dest, inverse-swizzled global source
  const int rT = tid >> 3, sd = tid & 7, sl = sd ^ (rT & 7);
  const ushort_t* srcA = hbf + (sl < 4 ? sl * 8 : 1024 + (sl - 4) * 8);
  const ushort_t* srcB = (sl < 4) ? (prBf + sl * 8) : (piBf + (sl - 4) * 8);
  const int dBase = (tid & ~63) * 8;

  f32x16 accr[2][2], acci[2][2];
#pragma unroll
  for (int mi = 0; mi < 2; ++mi)
#pragma unroll
    for (int ni = 0; ni < 2; ++ni) {
      accr[mi][ni] = (f32x16)(0.f);
      acci[mi][ni] = (f32x16)(0.f);
    }

  // prologue: stage tile 0 into buf 0
#pragma unroll
  for (int i = 0; i < 4; ++i)
    gload_lds16(srcA + (size_t)(b0 + i * 64 + rT) * K2DIM, (void*)(smem + i * 4096 + dBase));
#pragma unroll
  for (int i = 0; i < 2; ++i)
    gload_lds16(srcB + (size_t)(g0 + i * 64 + rT) * N_DIM, (void*)(smem + 16384 + i * 4096 + dBase));
  asm volatile("s_waitcnt vmcnt(0)" ::: "memory");
  __builtin_amdgcn_s_barrier();

  bf16x8 aL[2][2], aH[2][2], prB[2][2], piB[2][2], prN[2][2];

  // pre-read aL + prB of tile 0 (8 reads outstanding entering the loop)
  {
    const ushort_t* buf = smem;
#pragma unroll
    for (int mi = 0; mi < 2; ++mi)
#pragma unroll
      for (int ks = 0; ks < 2; ++ks)
        aL[mi][ks] = *(const bf16x8*)&buf[rowA[mi] + colL[ks]];
#pragma unroll
    for (int ni = 0; ni < 2; ++ni)
#pragma unroll
      for (int ks = 0; ks < 2; ++ks)
        prB[ni][ks] = *(const bf16x8*)&buf[rowB[ni] + colL[ks]];
  }

  for (int t = 0; t < 32; ++t) {
    const ushort_t* buf = smem + (t & 1) * 24576;
    const int nb = ((t + 1) & 1) * 24576;
    const int kp = (t + 1) * 32;
    const bool pf = (t < 31);

    // ---- P0: read piB; stage A(0,1); S0: accr += aL*pr
#pragma unroll
    for (int ni = 0; ni < 2; ++ni)
#pragma unroll
      for (int ks = 0; ks < 2; ++ks)
        piB[ni][ks] = *(const bf16x8*)&buf[rowB[ni] + colH[ks]];
    if (pf) {
#pragma unroll
      for (int i = 0; i < 2; ++i)
        gload_lds16(srcA + (size_t)(b0 + i * 64 + rT) * K2DIM + kp,
                    (void*)(smem + nb + i * 4096 + dBase));
    }
    LGKM(4); SB0();
    __builtin_amdgcn_s_setprio(1);
#pragma unroll
    for (int mi = 0; mi < 2; ++mi)
#pragma unroll
      for (int ni = 0; ni < 2; ++ni)
#pragma unroll
        for (int ks = 0; ks < 2; ++ks)
          accr[mi][ni] = __builtin_amdgcn_mfma_f32_32x32x16_bf16(aL[mi][ks], prB[ni][ks], accr[mi][ni], 0, 0, 0);
    __builtin_amdgcn_s_setprio(0);

    // ---- P1: read aH; stage A(2,3) + B(0,1); S1: acci += aL*pi
#pragma unroll
    for (int mi = 0; mi < 2; ++mi)
#pragma unroll
      for (int ks = 0; ks < 2; ++ks)
        aH[mi][ks] = *(const bf16x8*)&buf[rowA[mi] + colH[ks]];
    if (pf) {
#pragma unroll
      for (int i = 0; i < 2; ++i)
        gload_lds16(srcA + (size_t)(b0 + (i + 2) * 64 + rT) * K2DIM + kp,
                    (void*)(smem + nb + (i + 2) * 4096 + dBase));
#pragma unroll
      for (int i = 0; i < 2; ++i)
        gload_lds16(srcB + (size_t)(g0 + i * 64 + rT) * N_DIM + kp,
                    (void*)(smem + nb + 16384 + i * 4096 + dBase));
    }
    LGKM(4); SB0();
    __builtin_amdgcn_s_setprio(1);
#pragma unroll
    for (int mi = 0; mi < 2; ++mi)
#pragma unroll
      for (int ni = 0; ni < 2; ++ni)
#pragma unroll
        for (int ks = 0; ks < 2; ++ks)
          acci[mi][ni] = __builtin_amdgcn_mfma_f32_32x32x16_bf16(aL[mi][ks], piB[ni][ks], acci[mi][ni], 0, 0, 0);
    __builtin_amdgcn_s_setprio(0);

    // ---- P2: prN = -prB; S2: accr += aH*pi
#pragma unroll
    for (int ni = 0; ni < 2; ++ni)
#pragma unroll
      for (int ks = 0; ks < 2; ++ks)
        prN[ni][ks] = negbf(prB[ni][ks]);
    LGKM(0); SB0();
    __builtin_amdgcn_s_setprio(1);
#pragma unroll
    for (int mi = 0; mi < 2; ++mi)
#pragma unroll
      for (int ni = 0; ni < 2; ++ni)
#pragma unroll
        for (int ks = 0; ks < 2; ++ks)
          accr[mi][ni] = __builtin_amdgcn_mfma_f32_32x32x16_bf16(aH[mi][ks], piB[ni][ks], accr[mi][ni], 0, 0, 0);
    __builtin_amdgcn_s_setprio(0);

    // ---- P3: tile boundary; pre-read next aL+prB; S3: acci += aH*(-pr)
    if (pf) {
      asm volatile("s_waitcnt vmcnt(0)" ::: "memory");
      __builtin_amdgcn_s_barrier();
      const ushort_t* bn = smem + nb;
#pragma unroll
      for (int mi = 0; mi < 2; ++mi)
#pragma unroll
        for (int ks = 0; ks < 2; ++ks)
          aL[mi][ks] = *(const bf16x8*)&bn[rowA[mi] + colL[ks]];
#pragma unroll
      for (int ni = 0; ni < 2; ++ni)
#pragma unroll
        for (int ks = 0; ks < 2; ++ks)
          prB[ni][ks] = *(const bf16x8*)&bn[rowB[ni] + colL[ks]];
      SB0();
    }
    __builtin_amdgcn_s_setprio(1);
#pragma unroll
    for (int mi = 0; mi < 2; ++mi)
#pragma unroll
      for (int ni = 0; ni < 2; ++ni)
#pragma unroll
        for (int ks = 0; ks < 2; ++ks)
          acci[mi][ni] = __builtin_amdgcn_mfma_f32_32x32x16_bf16(aH[mi][ks], prN[ni][ks], acci[mi][ni], 0, 0, 0);
    __builtin_amdgcn_s_setprio(0);
  }

  // epilogue: |x|^2 as bf16. C/D: col=l&31, row=(reg&3)+8*(reg>>2)+4*(l>>5)
  const int rb0 = wm * 64 + 4 * (l >> 5);
#pragma unroll
  for (int mi = 0; mi < 2; ++mi)
#pragma unroll
    for (int ni = 0; ni < 2; ++ni) {
      const int gcol = g0 + wn * 64 + ni * 32 + (l & 31);
      const f32x16 r = accr[mi][ni], q = acci[mi][ni];
#pragma unroll
      for (int reg = 0; reg < 16; ++reg) {
        const int row = rb0 + mi * 32 + (reg & 3) + 8 * (reg >> 2);
        xabsBf[(size_t)(b0 + row) * G_DIM + gcol] = f2bf(r[reg] * r[reg] + q[reg] * q[reg]);
      }
    }
}

// ---------- K3: fused scan + fp64 refine + y + imag-zero + imag-scatter ----
__global__ __launch_bounds__(256) void k_sry(
    const ushort_t* __restrict__ xb, const float* __restrict__ H,
    const float* __restrict__ prT, const float* __restrict__ piT,
    int* __restrict__ wg, float* __restrict__ wxr, float* __restrict__ wxi,
    float* __restrict__ out) {
  __shared__ float red[4];
  __shared__ int scnt;
  __shared__ int scand[64];
  __shared__ double dred[8];
  __shared__ int sbg;
  __shared__ float sxr, sxi;
  const int b = blockIdx.x, tid = threadIdx.x;
  const int l = tid & 63, w = tid >> 6;
  // ---- scan phase: bf16 row (8KB), block max, candidates within 0.25
  const ushort_t* row = xb + (size_t)b * G_DIM + tid * 16;
  const u16x8 u0 = *(const u16x8*)row;
  const u16x8 u1 = *(const u16x8*)(row + 8);
  float v[16];
#pragma unroll
  for (int j = 0; j < 8; ++j) { v[j] = bf2f(u0[j]); v[8 + j] = bf2f(u1[j]); }
  float m = v[0];
#pragma unroll
  for (int j = 1; j < 16; ++j) m = fmaxf(m, v[j]);
#pragma unroll
  for (int off = 32; off; off >>= 1) m = fmaxf(m, __shfl_xor(m, off));
  if (tid == 0) scnt = 0;
  if (l == 0) red[w] = m;
  __syncthreads();
  const float thr = fmaxf(fmaxf(red[0], red[1]), fmaxf(red[2], red[3])) - 0.25f;
#pragma unroll
  for (int j = 0; j < 16; ++j)
    if (v[j] >= thr) { int p = atomicAdd(&scnt, 1); if (p < 64) scand[p] = tid * 16 + j; }
  __syncthreads();
  int cnt = scnt;
  if (cnt > 64) cnt = 64;
  // ---- refine phase: hoisted H (each thread owns n = tid*4 .. tid*4+3)
  const int n0 = tid * 4;
  const float4 hr4 = *reinterpret_cast<const float4*>(H + (size_t)b * N_DIM + n0);
  const float4 hi4 = *reinterpret_cast<const float4*>(H + (size_t)B_DIM * N_DIM + (size_t)b * N_DIM + n0);
  double best = -1.0, bxr = 0.0, bxi = 0.0;
  int bg = 0;
  for (int ci = 0; ci < cnt; ++ci) {
    const int g = scand[ci];
    const float4 p4 = *reinterpret_cast<const float4*>(prT + (size_t)g * N_DIM + n0);
    const float4 q4 = *reinterpret_cast<const float4*>(piT + (size_t)g * N_DIM + n0);
    double xr = (double)hr4.x * p4.x - (double)hi4.x * q4.x;
    double xi = (double)hr4.x * q4.x + (double)hi4.x * p4.x;
    xr += (double)hr4.y * p4.y - (double)hi4.y * q4.y;
    xi += (double)hr4.y * q4.y + (double)hi4.y * p4.y;
    xr += (double)hr4.z * p4.z - (double)hi4.z * q4.z;
    xi += (double)hr4.z * q4.z + (double)hi4.z * p4.z;
    xr += (double)hr4.w * p4.w - (double)hi4.w * q4.w;
    xi += (double)hr4.w * q4.w + (double)hi4.w * p4.w;
    for (int off = 32; off; off >>= 1) {
      xr += __shfl_down(xr, off);
      xi += __shfl_down(xi, off);
    }
    if (l == 0) { dred[w * 2] = xr; dred[w * 2 + 1] = xi; }
    __syncthreads();
    if (tid == 0) {
      const double sxrr = dred[0] + dred[2] + dred[4] + dred[6];
      const double sxii = dred[1] + dred[3] + dred[5] + dred[7];
      const double xab = sxrr * sxrr + sxii * sxii;
      if (xab > best || (xab == best && g < bg)) { best = xab; bg = g; bxr = sxrr; bxi = sxii; }
    }
    __syncthreads();
  }
  if (tid == 0) {
    wg[b] = bg; wxr[b] = (float)bxr; wxi[b] = (float)bxi;
    sbg = bg; sxr = (float)bxr; sxi = (float)bxi;
  }
  __syncthreads();
  // ---- y phase (f32 psi, winner column); y region is free (xabs lives in ws)
  const int g = sbg;
  const float xr = sxr, xi = sxi;
  const float4 p4 = *reinterpret_cast<const float4*>(prT + (size_t)g * N_DIM + n0);
  const float4 q4 = *reinterpret_cast<const float4*>(piT + (size_t)g * N_DIM + n0);
  float4 vr, vi;
  vr.x = xr * p4.x + xi * q4.x; vi.x = xi * p4.x - xr * q4.x;
  vr.y = xr * p4.y + xi * q4.y; vi.y = xi * p4.y - xr * q4.y;
  vr.z = xr * p4.z + xi * q4.z; vi.z = xi * p4.z - xr * q4.z;
  vr.w = xr * p4.w + xi * q4.w; vi.w = xi * p4.w - xr * q4.w;
  float* yr = out + (size_t)2 * B_DIM * G_DIM + (size_t)b * N_DIM;
  float* yi = yr + (size_t)B_DIM * N_DIM;
  *reinterpret_cast<float4*>(yr + n0) = vr;
  *reinterpret_cast<float4*>(yi + n0) = vi;
  // ---- zero x-imag row b (holds nothing) + scatter imag
  const float4 z = {0.f, 0.f, 0.f, 0.f};
  float* zi = out + (size_t)B_DIM * G_DIM + (size_t)b * G_DIM + tid * 16;
#pragma unroll
  for (int j = 0; j < 4; ++j) *reinterpret_cast<float4*>(zi + j * 4) = z;
  __syncthreads();
  if (tid == 0)
    out[(size_t)B_DIM * G_DIM + (size_t)b * G_DIM + g] = xi;
}

// ---------- K4: zero x-real plane (psi scratch now dead) + real scatter ----
__global__ __launch_bounds__(256) void k_fin(const int* __restrict__ wg,
                                             const float* __restrict__ wxr,
                                             float* __restrict__ out) {
  const int b = blockIdx.x, tid = threadIdx.x;
  const float4 z = {0.f, 0.f, 0.f, 0.f};
  float* zr = out + (size_t)b * G_DIM + tid * 16;
#pragma unroll
  for (int j = 0; j < 4; ++j) *reinterpret_cast<float4*>(zr + j * 4) = z;
  __syncthreads();
  if (tid == 0) out[(size_t)b * G_DIM + wg[b]] = wxr[b];
}

extern "C" void kernel_launch(void* const* d_in, const int* in_sizes, int n_in,
                              void* d_out, int out_size, void* d_ws, size_t ws_size,
                              hipStream_t stream) {
  const float* H = (const float*)d_in[0];
  const float* theta = (const float*)d_in[1];
  const float* alpha = (const float*)d_in[2];
  float* out = (float*)d_out;
  char* ws = (char*)d_ws;

  ushort_t* prBf = (ushort_t*)(ws + WS_PRBF);
  ushort_t* piBf = (ushort_t*)(ws + WS_PIBF);
  ushort_t* hbf = (ushort_t*)(ws + WS_HBF);
  ushort_t* xabsBf = (ushort_t*)(ws + WS_XABS);
  int* wg = (int*)(ws + WS_WG);
  float* wxr = (float*)(ws + WS_WXR);
  float* wxi = (float*)(ws + WS_WXI);

  // d_out scratch: x-real plane holds prT/piT until k_fin zeroes it
  float* prT = out;                          // [G][N] f32 (16 MB)
  float* piT = out + 4194304;                // [G][N] f32 (16 MB)

  k_prep<<<8192, 256, 0, stream>>>(theta, alpha, H, prT, piT, prBf, piBf, hbf);
  k_gemm<<<256, 512, 0, stream>>>(hbf, prBf, piBf, xabsBf);
  k_sry<<<B_DIM, 256, 0, stream>>>(xabsBf, H, prT, piT, wg, wxr, wxi, out);
  k_fin<<<B_DIM, 256, 0, stream>>>(wg, wxr, out);
}

// Round 17
// 113.083 us; speedup vs baseline: 1.1375x; 1.0832x over previous
//
#include <hip/hip_runtime.h>
#include <math.h>

#define N_DIM 1024
#define G_DIM 4096
#define B_DIM 2048
#define K2DIM 2048  // 2*N (real|imag concatenated K)

typedef __attribute__((ext_vector_type(8))) short bf16x8;
typedef __attribute__((ext_vector_type(8))) unsigned short u16x8;
typedef __attribute__((ext_vector_type(16))) float f32x16;
typedef unsigned short ushort_t;

// ---------- ws layout (bytes) ----------
#define WS_PRBF  0u                      // bf16 [G][1024]   8 MB
#define WS_PIBF  (8u << 20)              // bf16 [G][1024]   8 MB
#define WS_HBF   (16u << 20)             // bf16 [B][2048]   8 MB ([Hr | -Hi])
#define WS_XABS  (24u << 20)             // bf16 [B][G]     16 MB
#define WS_WG    (40u << 20)             // int [B]
#define WS_WXR   (WS_WG + 8192u)         // f32 [B]
#define WS_WXI   (WS_WXR + 8192u)        // f32 [B]
#define WS_PRT   (41u << 20)             // f32 [G][1024]  16 MB (optional)
#define WS_PIT   (57u << 20)             // f32 [G][1024]  16 MB (optional)
#define WS_BIG   (73u << 20)             // required ws_size for ws-psi path

__device__ __forceinline__ unsigned short f2bf(float f) {
  unsigned u = __float_as_uint(f);
  unsigned r = u + 0x7fffu + ((u >> 16) & 1u);
  return (unsigned short)(r >> 16);
}
__device__ __forceinline__ float bf2f(unsigned short u) {
  return __uint_as_float(((unsigned)u) << 16);
}
__device__ __forceinline__ bf16x8 negbf(bf16x8 v) {
  union { bf16x8 b; uint4 u; } x;
  x.b = v;
  x.u.x ^= 0x80008000u; x.u.y ^= 0x80008000u;
  x.u.z ^= 0x80008000u; x.u.w ^= 0x80008000u;
  return x.b;
}
// fast tanh via v_exp_f32 (alpha in [0,1) -> no overflow concerns)
__device__ __forceinline__ float tanh_fast(float x) {
  const float t = __expf(2.0f * x);
  return __fdividef(t - 1.0f, t + 1.0f);
}

__device__ __forceinline__ void gload_lds16(const void* gsrc, void* ldst) {
  __builtin_amdgcn_global_load_lds(
      (const __attribute__((address_space(1))) void*)gsrc,
      (__attribute__((address_space(3))) void*)ldst, 16, 0, 0);
}

// ---------- K1: fused PSI generation + H conversion (vectorized) ------
__global__ __launch_bounds__(256) void k_prep(
    const float* __restrict__ theta, const float* __restrict__ alpha,
    const float* __restrict__ H,
    float* __restrict__ prT, float* __restrict__ piT,
    ushort_t* __restrict__ prBf, ushort_t* __restrict__ piBf,
    ushort_t* __restrict__ hbf) {
  __shared__ float sp[32][33], si[32][33];
  const int bid = blockIdx.x, tid = threadIdx.x;
  if (bid < 4096) {
    // PSI: 32n x 32g tile; float4 reads, one pass (8 thr/row x 32 rows)
    const int g0 = (bid & 127) * 32, n0 = (bid >> 7) * 32;
    const int c4 = (tid & 7) * 4, row = tid >> 3;
    const size_t idx = (size_t)(n0 + row) * G_DIM + g0 + c4;
    const float4 a4 = *reinterpret_cast<const float4*>(alpha + idx);
    const float4 t4 = *reinterpret_cast<const float4*>(theta + idx);
#pragma unroll
    for (int j = 0; j < 4; ++j) {
      const float av = (j == 0) ? a4.x : (j == 1) ? a4.y : (j == 2) ? a4.z : a4.w;
      const float tv = (j == 0) ? t4.x : (j == 1) ? t4.y : (j == 2) ? t4.z : t4.w;
      const float a = tanh_fast(av) * 0.03125f;  // 1/sqrt(1024)
      sp[row][c4 + j] = a * __cosf(tv);
      si[row][c4 + j] = a * __sinf(tv);
    }
    __syncthreads();
    // write: g = g0 + row, n-quad = n0 + c4; float4 / ushort4 stores
    const size_t obase = (size_t)(g0 + row) * N_DIM + n0 + c4;
    float4 vr, vi;
    ushort4 ur, ui;
#pragma unroll
    for (int j = 0; j < 4; ++j) {
      const float pr = sp[c4 + j][row], pi = si[c4 + j][row];
      if (j == 0) { vr.x = pr; vi.x = pi; ur.x = f2bf(pr); ui.x = f2bf(pi); }
      else if (j == 1) { vr.y = pr; vi.y = pi; ur.y = f2bf(pr); ui.y = f2bf(pi); }
      else if (j == 2) { vr.z = pr; vi.z = pi; ur.z = f2bf(pr); ui.z = f2bf(pi); }
      else { vr.w = pr; vi.w = pi; ur.w = f2bf(pr); ui.w = f2bf(pi); }
    }
    *reinterpret_cast<float4*>(prT + obase) = vr;
    *reinterpret_cast<float4*>(piT + obase) = vi;
    *reinterpret_cast<ushort4*>(prBf + obase) = ur;
    *reinterpret_cast<ushort4*>(piBf + obase) = ui;
  } else {
    // H -> bf16, layout [B][2048] = [Hr | -Hi]
    const int j4 = ((bid - 4096) * 256 + tid) * 4;
    const int b = j4 >> 11, k = j4 & 2047, c = k >> 10, n = k & 1023;
    float4 v = *reinterpret_cast<const float4*>(
        H + (size_t)c * (B_DIM * N_DIM) + (size_t)b * N_DIM + n);
    if (c) { v.x = -v.x; v.y = -v.y; v.z = -v.z; v.w = -v.w; }
    ushort4 u;
    u.x = f2bf(v.x); u.y = f2bf(v.y); u.z = f2bf(v.z); u.w = f2bf(v.w);
    *reinterpret_cast<ushort4*>(hbf + j4) = u;
  }
}

#define LGKM(n) asm volatile("s_waitcnt lgkmcnt(" #n ")" ::: "memory")
#define SB0() __builtin_amdgcn_sched_barrier(0)

// ---------- K2: merged-B 32x32x16 dual-acc GEMM -> |x|^2 (bf16) ----------
// Best-measured core (62.8us): BM=256, BN=128, merged 32 k-lo + 32 k-hi.
// 8 waves 4M x 2N. LDS 2-ring x 48KB = 96KB; slot ^= row&7.
// accr = aL*pr + aH*pi ; acci = aL*pi + aH*(-pr)   (aH = -Hi)
__global__ __launch_bounds__(512, 2) void k_gemm(
    const ushort_t* __restrict__ hbf, const ushort_t* __restrict__ prBf,
    const ushort_t* __restrict__ piBf, ushort_t* __restrict__ xabsBf) {
  __shared__ ushort_t smem[49152];     // 96 KB: 2 bufs x 24576 ushorts
  const int tid = threadIdx.x;
  const int l = tid & 63, w = tid >> 6;
  const int wm = w >> 1, wn = w & 1;   // 4M x 2N
  const int bid = blockIdx.x;
  const int xcd = bid & 7, idx = bid >> 3;
  const int g0 = (xcd * 4 + (idx & 3)) * 128;
  const int b0 = (idx >> 2) * 256;

  // fragment offsets: rows 64 ushorts (128 B), slot ^= row&7 (row&7 == l&7)
  const int h = l >> 5;
  int colL[2], colH[2];
#pragma unroll
  for (int ks = 0; ks < 2; ++ks) {
    colL[ks] = ((ks * 2 + h) ^ (l & 7)) * 8;
    colH[ks] = ((4 + ks * 2 + h) ^ (l & 7)) * 8;
  }
  int rowA[2], rowB[2];
#pragma unroll
  for (int mi = 0; mi < 2; ++mi) rowA[mi] = (wm * 64 + mi * 32 + (l & 31)) * 64;
#pragma unroll
  for (int ni = 0; ni < 2; ++ni) rowB[ni] = 16384 + (wn * 64 + ni * 32 + (l & 31)) * 64;

  // staging: linear LDS dest, inverse-swizzled global source
  const int rT = tid >> 3, sd = tid & 7, sl = sd ^ (rT & 7);
  const ushort_t* srcA = hbf + (sl < 4 ? sl * 8 : 1024 + (sl - 4) * 8);
  const ushort_t* srcB = (sl < 4) ? (prBf + sl * 8) : (piBf + (sl - 4) * 8);
  const int dBase = (tid & ~63) * 8;

  f32x16 accr[2][2], acci[2][2];
#pragma unroll
  for (int mi = 0; mi < 2; ++mi)
#pragma unroll
    for (int ni = 0; ni < 2; ++ni) {
      accr[mi][ni] = (f32x16)(0.f);
      acci[mi][ni] = (f32x16)(0.f);
    }

  // prologue: stage tile 0 into buf 0
#pragma unroll
  for (int i = 0; i < 4; ++i)
    gload_lds16(srcA + (size_t)(b0 + i * 64 + rT) * K2DIM, (void*)(smem + i * 4096 + dBase));
#pragma unroll
  for (int i = 0; i < 2; ++i)
    gload_lds16(srcB + (size_t)(g0 + i * 64 + rT) * N_DIM, (void*)(smem + 16384 + i * 4096 + dBase));
  asm volatile("s_waitcnt vmcnt(0)" ::: "memory");
  __builtin_amdgcn_s_barrier();

  bf16x8 aL[2][2], aH[2][2], prB[2][2], piB[2][2], prN[2][2];

  // pre-read aL + prB of tile 0 (8 reads outstanding entering the loop)
  {
    const ushort_t* buf = smem;
#pragma unroll
    for (int mi = 0; mi < 2; ++mi)
#pragma unroll
      for (int ks = 0; ks < 2; ++ks)
        aL[mi][ks] = *(const bf16x8*)&buf[rowA[mi] + colL[ks]];
#pragma unroll
    for (int ni = 0; ni < 2; ++ni)
#pragma unroll
      for (int ks = 0; ks < 2; ++ks)
        prB[ni][ks] = *(const bf16x8*)&buf[rowB[ni] + colL[ks]];
  }

  for (int t = 0; t < 32; ++t) {
    const ushort_t* buf = smem + (t & 1) * 24576;
    const int nb = ((t + 1) & 1) * 24576;
    const int kp = (t + 1) * 32;
    const bool pf = (t < 31);

    // ---- P0: read piB; stage A(0,1); S0: accr += aL*pr
#pragma unroll
    for (int ni = 0; ni < 2; ++ni)
#pragma unroll
      for (int ks = 0; ks < 2; ++ks)
        piB[ni][ks] = *(const bf16x8*)&buf[rowB[ni] + colH[ks]];
    if (pf) {
#pragma unroll
      for (int i = 0; i < 2; ++i)
        gload_lds16(srcA + (size_t)(b0 + i * 64 + rT) * K2DIM + kp,
                    (void*)(smem + nb + i * 4096 + dBase));
    }
    LGKM(4); SB0();
    __builtin_amdgcn_s_setprio(1);
#pragma unroll
    for (int mi = 0; mi < 2; ++mi)
#pragma unroll
      for (int ni = 0; ni < 2; ++ni)
#pragma unroll
        for (int ks = 0; ks < 2; ++ks)
          accr[mi][ni] = __builtin_amdgcn_mfma_f32_32x32x16_bf16(aL[mi][ks], prB[ni][ks], accr[mi][ni], 0, 0, 0);
    __builtin_amdgcn_s_setprio(0);

    // ---- P1: read aH; stage A(2,3) + B(0,1); S1: acci += aL*pi
#pragma unroll
    for (int mi = 0; mi < 2; ++mi)
#pragma unroll
      for (int ks = 0; ks < 2; ++ks)
        aH[mi][ks] = *(const bf16x8*)&buf[rowA[mi] + colH[ks]];
    if (pf) {
#pragma unroll
      for (int i = 0; i < 2; ++i)
        gload_lds16(srcA + (size_t)(b0 + (i + 2) * 64 + rT) * K2DIM + kp,
                    (void*)(smem + nb + (i + 2) * 4096 + dBase));
#pragma unroll
      for (int i = 0; i < 2; ++i)
        gload_lds16(srcB + (size_t)(g0 + i * 64 + rT) * N_DIM + kp,
                    (void*)(smem + nb + 16384 + i * 4096 + dBase));
    }
    LGKM(4); SB0();
    __builtin_amdgcn_s_setprio(1);
#pragma unroll
    for (int mi = 0; mi < 2; ++mi)
#pragma unroll
      for (int ni = 0; ni < 2; ++ni)
#pragma unroll
        for (int ks = 0; ks < 2; ++ks)
          acci[mi][ni] = __builtin_amdgcn_mfma_f32_32x32x16_bf16(aL[mi][ks], piB[ni][ks], acci[mi][ni], 0, 0, 0);
    __builtin_amdgcn_s_setprio(0);

    // ---- P2: prN = -prB; S2: accr += aH*pi
#pragma unroll
    for (int ni = 0; ni < 2; ++ni)
#pragma unroll
      for (int ks = 0; ks < 2; ++ks)
        prN[ni][ks] = negbf(prB[ni][ks]);
    LGKM(0); SB0();
    __builtin_amdgcn_s_setprio(1);
#pragma unroll
    for (int mi = 0; mi < 2; ++mi)
#pragma unroll
      for (int ni = 0; ni < 2; ++ni)
#pragma unroll
        for (int ks = 0; ks < 2; ++ks)
          accr[mi][ni] = __builtin_amdgcn_mfma_f32_32x32x16_bf16(aH[mi][ks], piB[ni][ks], accr[mi][ni], 0, 0, 0);
    __builtin_amdgcn_s_setprio(0);

    // ---- P3: tile boundary; pre-read next aL+prB; S3: acci += aH*(-pr)
    if (pf) {
      asm volatile("s_waitcnt vmcnt(0)" ::: "memory");
      __builtin_amdgcn_s_barrier();
      const ushort_t* bn = smem + nb;
#pragma unroll
      for (int mi = 0; mi < 2; ++mi)
#pragma unroll
        for (int ks = 0; ks < 2; ++ks)
          aL[mi][ks] = *(const bf16x8*)&bn[rowA[mi] + colL[ks]];
#pragma unroll
      for (int ni = 0; ni < 2; ++ni)
#pragma unroll
        for (int ks = 0; ks < 2; ++ks)
          prB[ni][ks] = *(const bf16x8*)&bn[rowB[ni] + colL[ks]];
      SB0();
    }
    __builtin_amdgcn_s_setprio(1);
#pragma unroll
    for (int mi = 0; mi < 2; ++mi)
#pragma unroll
      for (int ni = 0; ni < 2; ++ni)
#pragma unroll
        for (int ks = 0; ks < 2; ++ks)
          acci[mi][ni] = __builtin_amdgcn_mfma_f32_32x32x16_bf16(aH[mi][ks], prN[ni][ks], acci[mi][ni], 0, 0, 0);
    __builtin_amdgcn_s_setprio(0);
  }

  // epilogue: |x|^2 as bf16. C/D: col=l&31, row=(reg&3)+8*(reg>>2)+4*(l>>5)
  const int rb0 = wm * 64 + 4 * (l >> 5);
#pragma unroll
  for (int mi = 0; mi < 2; ++mi)
#pragma unroll
    for (int ni = 0; ni < 2; ++ni) {
      const int gcol = g0 + wn * 64 + ni * 32 + (l & 31);
      const f32x16 r = accr[mi][ni], q = acci[mi][ni];
#pragma unroll
      for (int reg = 0; reg < 16; ++reg) {
        const int row = rb0 + mi * 32 + (reg & 3) + 8 * (reg >> 2);
        xabsBf[(size_t)(b0 + row) * G_DIM + gcol] = f2bf(r[reg] * r[reg] + q[reg] * q[reg]);
      }
    }
}

// ---------- K3: fused scan + fp64 refine + y + zero/scatter ----------
// zeroReal=1 (psi in ws): zero+scatter BOTH x planes here (no k_fin).
// zeroReal=0 (psi in out x-real plane): only imag here; k_fin does real.
__global__ __launch_bounds__(256) void k_sry(
    const ushort_t* __restrict__ xb, const float* __restrict__ H,
    const float* __restrict__ prT, const float* __restrict__ piT,
    int* __restrict__ wg, float* __restrict__ wxr, float* __restrict__ wxi,
    float* __restrict__ out, const int zeroReal) {
  __shared__ float red[4];
  __shared__ int scnt;
  __shared__ int scand[64];
  __shared__ double dred[8];
  __shared__ int sbg;
  __shared__ float sxr, sxi;
  const int b = blockIdx.x, tid = threadIdx.x;
  const int l = tid & 63, w = tid >> 6;
  // ---- scan phase: bf16 row (8KB), block max, candidates within 0.25
  const ushort_t* row = xb + (size_t)b * G_DIM + tid * 16;
  const u16x8 u0 = *(const u16x8*)row;
  const u16x8 u1 = *(const u16x8*)(row + 8);
  float v[16];
#pragma unroll
  for (int j = 0; j < 8; ++j) { v[j] = bf2f(u0[j]); v[8 + j] = bf2f(u1[j]); }
  float m = v[0];
#pragma unroll
  for (int j = 1; j < 16; ++j) m = fmaxf(m, v[j]);
#pragma unroll
  for (int off = 32; off; off >>= 1) m = fmaxf(m, __shfl_xor(m, off));
  if (tid == 0) scnt = 0;
  if (l == 0) red[w] = m;
  __syncthreads();
  const float thr = fmaxf(fmaxf(red[0], red[1]), fmaxf(red[2], red[3])) - 0.25f;
#pragma unroll
  for (int j = 0; j < 16; ++j)
    if (v[j] >= thr) { int p = atomicAdd(&scnt, 1); if (p < 64) scand[p] = tid * 16 + j; }
  __syncthreads();
  int cnt = scnt;
  if (cnt > 64) cnt = 64;
  // ---- refine phase: hoisted H (each thread owns n = tid*4 .. tid*4+3)
  const int n0 = tid * 4;
  const float4 hr4 = *reinterpret_cast<const float4*>(H + (size_t)b * N_DIM + n0);
  const float4 hi4 = *reinterpret_cast<const float4*>(H + (size_t)B_DIM * N_DIM + (size_t)b * N_DIM + n0);
  double best = -1.0, bxr = 0.0, bxi = 0.0;
  int bg = 0;
  for (int ci = 0; ci < cnt; ++ci) {
    const int g = scand[ci];
    const float4 p4 = *reinterpret_cast<const float4*>(prT + (size_t)g * N_DIM + n0);
    const float4 q4 = *reinterpret_cast<const float4*>(piT + (size_t)g * N_DIM + n0);
    double xr = (double)hr4.x * p4.x - (double)hi4.x * q4.x;
    double xi = (double)hr4.x * q4.x + (double)hi4.x * p4.x;
    xr += (double)hr4.y * p4.y - (double)hi4.y * q4.y;
    xi += (double)hr4.y * q4.y + (double)hi4.y * p4.y;
    xr += (double)hr4.z * p4.z - (double)hi4.z * q4.z;
    xi += (double)hr4.z * q4.z + (double)hi4.z * p4.z;
    xr += (double)hr4.w * p4.w - (double)hi4.w * q4.w;
    xi += (double)hr4.w * q4.w + (double)hi4.w * p4.w;
    for (int off = 32; off; off >>= 1) {
      xr += __shfl_down(xr, off);
      xi += __shfl_down(xi, off);
    }
    if (l == 0) { dred[w * 2] = xr; dred[w * 2 + 1] = xi; }
    __syncthreads();
    if (tid == 0) {
      const double sxrr = dred[0] + dred[2] + dred[4] + dred[6];
      const double sxii = dred[1] + dred[3] + dred[5] + dred[7];
      const double xab = sxrr * sxrr + sxii * sxii;
      if (xab > best || (xab == best && g < bg)) { best = xab; bg = g; bxr = sxrr; bxi = sxii; }
    }
    __syncthreads();
  }
  if (tid == 0) {
    wg[b] = bg; wxr[b] = (float)bxr; wxi[b] = (float)bxi;
    sbg = bg; sxr = (float)bxr; sxi = (float)bxi;
  }
  __syncthreads();
  // ---- y phase (f32 psi, winner column); y region is free (xabs lives in ws)
  const int g = sbg;
  const float xr = sxr, xi = sxi;
  const float4 p4 = *reinterpret_cast<const float4*>(prT + (size_t)g * N_DIM + n0);
  const float4 q4 = *reinterpret_cast<const float4*>(piT + (size_t)g * N_DIM + n0);
  float4 vr, vi;
  vr.x = xr * p4.x + xi * q4.x; vi.x = xi * p4.x - xr * q4.x;
  vr.y = xr * p4.y + xi * q4.y; vi.y = xi * p4.y - xr * q4.y;
  vr.z = xr * p4.z + xi * q4.z; vi.z = xi * p4.z - xr * q4.z;
  vr.w = xr * p4.w + xi * q4.w; vi.w = xi * p4.w - xr * q4.w;
  float* yr = out + (size_t)2 * B_DIM * G_DIM + (size_t)b * N_DIM;
  float* yi = yr + (size_t)B_DIM * N_DIM;
  *reinterpret_cast<float4*>(yr + n0) = vr;
  *reinterpret_cast<float4*>(yi + n0) = vi;
  // ---- zero x-imag row b (+ x-real row if psi lives in ws), then scatter
  const float4 z = {0.f, 0.f, 0.f, 0.f};
  float* zi = out + (size_t)B_DIM * G_DIM + (size_t)b * G_DIM + tid * 16;
#pragma unroll
  for (int j = 0; j < 4; ++j) *reinterpret_cast<float4*>(zi + j * 4) = z;
  if (zeroReal) {
    float* zr = out + (size_t)b * G_DIM + tid * 16;
#pragma unroll
    for (int j = 0; j < 4; ++j) *reinterpret_cast<float4*>(zr + j * 4) = z;
  }
  __syncthreads();
  if (tid == 0) {
    out[(size_t)B_DIM * G_DIM + (size_t)b * G_DIM + g] = xi;
    if (zeroReal) out[(size_t)b * G_DIM + g] = xr;
  }
}

// ---------- K4 (fallback only): zero x-real plane + real scatter ----------
__global__ __launch_bounds__(256) void k_fin(const int* __restrict__ wg,
                                             const float* __restrict__ wxr,
                                             float* __restrict__ out) {
  const int b = blockIdx.x, tid = threadIdx.x;
  const float4 z = {0.f, 0.f, 0.f, 0.f};
  float* zr = out + (size_t)b * G_DIM + tid * 16;
#pragma unroll
  for (int j = 0; j < 4; ++j) *reinterpret_cast<float4*>(zr + j * 4) = z;
  __syncthreads();
  if (tid == 0) out[(size_t)b * G_DIM + wg[b]] = wxr[b];
}

extern "C" void kernel_launch(void* const* d_in, const int* in_sizes, int n_in,
                              void* d_out, int out_size, void* d_ws, size_t ws_size,
                              hipStream_t stream) {
  const float* H = (const float*)d_in[0];
  const float* theta = (const float*)d_in[1];
  const float* alpha = (const float*)d_in[2];
  float* out = (float*)d_out;
  char* ws = (char*)d_ws;

  ushort_t* prBf = (ushort_t*)(ws + WS_PRBF);
  ushort_t* piBf = (ushort_t*)(ws + WS_PIBF);
  ushort_t* hbf = (ushort_t*)(ws + WS_HBF);
  ushort_t* xabsBf = (ushort_t*)(ws + WS_XABS);
  int* wg = (int*)(ws + WS_WG);
  float* wxr = (float*)(ws + WS_WXR);
  float* wxi = (float*)(ws + WS_WXI);

  // psi f32 scratch: ws if it fits (x-real plane stays clean -> no k_fin),
  // else the out x-real plane (R16-measured fallback path).
  const bool big = ws_size >= (size_t)WS_BIG;
  float* prT = big ? (float*)(ws + WS_PRT) : out;
  float* piT = big ? (float*)(ws + WS_PIT) : out + 4194304;

  k_prep<<<8192, 256, 0, stream>>>(theta, alpha, H, prT, piT, prBf, piBf, hbf);
  k_gemm<<<256, 512, 0, stream>>>(hbf, prBf, piBf, xabsBf);
  k_sry<<<B_DIM, 256, 0, stream>>>(xabsBf, H, prT, piT, wg, wxr, wxi, out, big ? 1 : 0);
  if (!big) k_fin<<<B_DIM, 256, 0, stream>>>(wg, wxr, out);
}

// Round 18
// 101.504 us; speedup vs baseline: 1.2673x; 1.1141x over previous
//
#include <hip/hip_runtime.h>
#include <math.h>

#define N_DIM 1024
#define G_DIM 4096
#define B_DIM 2048
#define K2DIM 2048  // 2*N (real|imag concatenated K)

typedef __attribute__((ext_vector_type(8))) short bf16x8;
typedef __attribute__((ext_vector_type(8))) unsigned short u16x8;
typedef __attribute__((ext_vector_type(16))) float f32x16;
typedef unsigned short ushort_t;

// ---------- ws layout (bytes) ----------
#define WS_PRBF  0u                      // bf16 [G][1024]   8 MB
#define WS_PIBF  (8u << 20)              // bf16 [G][1024]   8 MB
#define WS_HBF   (16u << 20)             // bf16 [B][2048]   8 MB ([Hr | -Hi])
#define WS_XABS  (24u << 20)             // bf16 [B][G]     16 MB
#define WS_WG    (40u << 20)             // int [B]
#define WS_WXR   (WS_WG + 8192u)         // f32 [B]
#define WS_WXI   (WS_WXR + 8192u)        // f32 [B]
#define WS_PRT   (41u << 20)             // f32 [G][1024]  16 MB (optional)
#define WS_PIT   (57u << 20)             // f32 [G][1024]  16 MB (optional)
#define WS_BIG   (73u << 20)             // required ws_size for ws-psi path

__device__ __forceinline__ unsigned short f2bf(float f) {
  unsigned u = __float_as_uint(f);
  unsigned r = u + 0x7fffu + ((u >> 16) & 1u);
  return (unsigned short)(r >> 16);
}
__device__ __forceinline__ float bf2f(unsigned short u) {
  return __uint_as_float(((unsigned)u) << 16);
}
__device__ __forceinline__ bf16x8 negbf(bf16x8 v) {
  union { bf16x8 b; uint4 u; } x;
  x.b = v;
  x.u.x ^= 0x80008000u; x.u.y ^= 0x80008000u;
  x.u.z ^= 0x80008000u; x.u.w ^= 0x80008000u;
  return x.b;
}
// fast tanh via v_exp_f32 (alpha in [0,1) -> no overflow concerns)
__device__ __forceinline__ float tanh_fast(float x) {
  const float t = __expf(2.0f * x);
  return __fdividef(t - 1.0f, t + 1.0f);
}

__device__ __forceinline__ void gload_lds16(const void* gsrc, void* ldst) {
  __builtin_amdgcn_global_load_lds(
      (const __attribute__((address_space(1))) void*)gsrc,
      (__attribute__((address_space(3))) void*)ldst, 16, 0, 0);
}

// ---------- K1: fused PSI generation + H conversion (vectorized) ------
__global__ __launch_bounds__(256) void k_prep(
    const float* __restrict__ theta, const float* __restrict__ alpha,
    const float* __restrict__ H,
    float* __restrict__ prT, float* __restrict__ piT,
    ushort_t* __restrict__ prBf, ushort_t* __restrict__ piBf,
    ushort_t* __restrict__ hbf) {
  __shared__ float sp[32][33], si[32][33];
  const int bid = blockIdx.x, tid = threadIdx.x;
  if (bid < 4096) {
    // PSI: 32n x 32g tile; float4 reads, one pass (8 thr/row x 32 rows)
    const int g0 = (bid & 127) * 32, n0 = (bid >> 7) * 32;
    const int c4 = (tid & 7) * 4, row = tid >> 3;
    const size_t idx = (size_t)(n0 + row) * G_DIM + g0 + c4;
    const float4 a4 = *reinterpret_cast<const float4*>(alpha + idx);
    const float4 t4 = *reinterpret_cast<const float4*>(theta + idx);
#pragma unroll
    for (int j = 0; j < 4; ++j) {
      const float av = (j == 0) ? a4.x : (j == 1) ? a4.y : (j == 2) ? a4.z : a4.w;
      const float tv = (j == 0) ? t4.x : (j == 1) ? t4.y : (j == 2) ? t4.z : t4.w;
      const float a = tanh_fast(av) * 0.03125f;  // 1/sqrt(1024)
      sp[row][c4 + j] = a * __cosf(tv);
      si[row][c4 + j] = a * __sinf(tv);
    }
    __syncthreads();
    // write: g = g0 + row, n-quad = n0 + c4; float4 / ushort4 stores
    const size_t obase = (size_t)(g0 + row) * N_DIM + n0 + c4;
    float4 vr, vi;
    ushort4 ur, ui;
#pragma unroll
    for (int j = 0; j < 4; ++j) {
      const float pr = sp[c4 + j][row], pi = si[c4 + j][row];
      if (j == 0) { vr.x = pr; vi.x = pi; ur.x = f2bf(pr); ui.x = f2bf(pi); }
      else if (j == 1) { vr.y = pr; vi.y = pi; ur.y = f2bf(pr); ui.y = f2bf(pi); }
      else if (j == 2) { vr.z = pr; vi.z = pi; ur.z = f2bf(pr); ui.z = f2bf(pi); }
      else { vr.w = pr; vi.w = pi; ur.w = f2bf(pr); ui.w = f2bf(pi); }
    }
    *reinterpret_cast<float4*>(prT + obase) = vr;
    *reinterpret_cast<float4*>(piT + obase) = vi;
    *reinterpret_cast<ushort4*>(prBf + obase) = ur;
    *reinterpret_cast<ushort4*>(piBf + obase) = ui;
  } else {
    // H -> bf16, layout [B][2048] = [Hr | -Hi]
    const int j4 = ((bid - 4096) * 256 + tid) * 4;
    const int b = j4 >> 11, k = j4 & 2047, c = k >> 10, n = k & 1023;
    float4 v = *reinterpret_cast<const float4*>(
        H + (size_t)c * (B_DIM * N_DIM) + (size_t)b * N_DIM + n);
    if (c) { v.x = -v.x; v.y = -v.y; v.z = -v.z; v.w = -v.w; }
    ushort4 u;
    u.x = f2bf(v.x); u.y = f2bf(v.y); u.z = f2bf(v.z); u.w = f2bf(v.w);
    *reinterpret_cast<ushort4*>(hbf + j4) = u;
  }
}

#define LGKM(n) asm volatile("s_waitcnt lgkmcnt(" #n ")" ::: "memory")
#define SB0() __builtin_amdgcn_sched_barrier(0)

// ---------- K2: merged-B 32x32x16 dual-acc GEMM -> |x|^2 (bf16) ----------
// Best-measured core (62.8us): BM=256, BN=128, merged 32 k-lo + 32 k-hi.
// 8 waves 4M x 2N. LDS 2-ring x 48KB = 96KB; slot ^= row&7.
// accr = aL*pr + aH*pi ; acci = aL*pi + aH*(-pr)   (aH = -Hi)
// If zeroX: also zero this block's disjoint 256x128 slice of BOTH x-planes,
// one float4 store/thread/tile (hidden under the compute-bound K-loop).
__global__ __launch_bounds__(512, 2) void k_gemm(
    const ushort_t* __restrict__ hbf, const ushort_t* __restrict__ prBf,
    const ushort_t* __restrict__ piBf, ushort_t* __restrict__ xabsBf,
    float* __restrict__ xout, const int zeroX) {
  __shared__ ushort_t smem[49152];     // 96 KB: 2 bufs x 24576 ushorts
  const int tid = threadIdx.x;
  const int l = tid & 63, w = tid >> 6;
  const int wm = w >> 1, wn = w & 1;   // 4M x 2N
  const int bid = blockIdx.x;
  const int xcd = bid & 7, idx = bid >> 3;
  const int g0 = (xcd * 4 + (idx & 3)) * 128;
  const int b0 = (idx >> 2) * 256;

  // fragment offsets: rows 64 ushorts (128 B), slot ^= row&7 (row&7 == l&7)
  const int h = l >> 5;
  int colL[2], colH[2];
#pragma unroll
  for (int ks = 0; ks < 2; ++ks) {
    colL[ks] = ((ks * 2 + h) ^ (l & 7)) * 8;
    colH[ks] = ((4 + ks * 2 + h) ^ (l & 7)) * 8;
  }
  int rowA[2], rowB[2];
#pragma unroll
  for (int mi = 0; mi < 2; ++mi) rowA[mi] = (wm * 64 + mi * 32 + (l & 31)) * 64;
#pragma unroll
  for (int ni = 0; ni < 2; ++ni) rowB[ni] = 16384 + (wn * 64 + ni * 32 + (l & 31)) * 64;

  // staging: linear LDS dest, inverse-swizzled global source
  const int rT = tid >> 3, sd = tid & 7, sl = sd ^ (rT & 7);
  const ushort_t* srcA = hbf + (sl < 4 ? sl * 8 : 1024 + (sl - 4) * 8);
  const ushort_t* srcB = (sl < 4) ? (prBf + sl * 8) : (piBf + (sl - 4) * 8);
  const int dBase = (tid & ~63) * 8;

  // x-plane zero-store base for this thread (pass p covers rows b0+p*16..+15)
  float* xz0 = xout + (size_t)(b0 + (tid >> 5)) * G_DIM + g0 + (tid & 31) * 4;

  f32x16 accr[2][2], acci[2][2];
#pragma unroll
  for (int mi = 0; mi < 2; ++mi)
#pragma unroll
    for (int ni = 0; ni < 2; ++ni) {
      accr[mi][ni] = (f32x16)(0.f);
      acci[mi][ni] = (f32x16)(0.f);
    }

  // prologue: stage tile 0 into buf 0
#pragma unroll
  for (int i = 0; i < 4; ++i)
    gload_lds16(srcA + (size_t)(b0 + i * 64 + rT) * K2DIM, (void*)(smem + i * 4096 + dBase));
#pragma unroll
  for (int i = 0; i < 2; ++i)
    gload_lds16(srcB + (size_t)(g0 + i * 64 + rT) * N_DIM, (void*)(smem + 16384 + i * 4096 + dBase));
  asm volatile("s_waitcnt vmcnt(0)" ::: "memory");
  __builtin_amdgcn_s_barrier();

  bf16x8 aL[2][2], aH[2][2], prB[2][2], piB[2][2], prN[2][2];

  // pre-read aL + prB of tile 0 (8 reads outstanding entering the loop)
  {
    const ushort_t* buf = smem;
#pragma unroll
    for (int mi = 0; mi < 2; ++mi)
#pragma unroll
      for (int ks = 0; ks < 2; ++ks)
        aL[mi][ks] = *(const bf16x8*)&buf[rowA[mi] + colL[ks]];
#pragma unroll
    for (int ni = 0; ni < 2; ++ni)
#pragma unroll
      for (int ks = 0; ks < 2; ++ks)
        prB[ni][ks] = *(const bf16x8*)&buf[rowB[ni] + colL[ks]];
  }

  for (int t = 0; t < 32; ++t) {
    const ushort_t* buf = smem + (t & 1) * 24576;
    const int nb = ((t + 1) & 1) * 24576;
    const int kp = (t + 1) * 32;
    const bool pf = (t < 31);

    // ---- P0: read piB; stage A(0,1); zero-store slice pass; S0: accr += aL*pr
#pragma unroll
    for (int ni = 0; ni < 2; ++ni)
#pragma unroll
      for (int ks = 0; ks < 2; ++ks)
        piB[ni][ks] = *(const bf16x8*)&buf[rowB[ni] + colH[ks]];
    if (pf) {
#pragma unroll
      for (int i = 0; i < 2; ++i)
        gload_lds16(srcA + (size_t)(b0 + i * 64 + rT) * K2DIM + kp,
                    (void*)(smem + nb + i * 4096 + dBase));
    }
    if (zeroX) {
      // tile t: pass t&15 of plane (t<16 ? real : imag)
      float* xz = xz0 + (size_t)(t & 15) * 16 * G_DIM
                + (t < 16 ? 0 : (size_t)B_DIM * G_DIM);
      *reinterpret_cast<float4*>(xz) = (float4){0.f, 0.f, 0.f, 0.f};
    }
    LGKM(4); SB0();
    __builtin_amdgcn_s_setprio(1);
#pragma unroll
    for (int mi = 0; mi < 2; ++mi)
#pragma unroll
      for (int ni = 0; ni < 2; ++ni)
#pragma unroll
        for (int ks = 0; ks < 2; ++ks)
          accr[mi][ni] = __builtin_amdgcn_mfma_f32_32x32x16_bf16(aL[mi][ks], prB[ni][ks], accr[mi][ni], 0, 0, 0);
    __builtin_amdgcn_s_setprio(0);

    // ---- P1: read aH; stage A(2,3) + B(0,1); S1: acci += aL*pi
#pragma unroll
    for (int mi = 0; mi < 2; ++mi)
#pragma unroll
      for (int ks = 0; ks < 2; ++ks)
        aH[mi][ks] = *(const bf16x8*)&buf[rowA[mi] + colH[ks]];
    if (pf) {
#pragma unroll
      for (int i = 0; i < 2; ++i)
        gload_lds16(srcA + (size_t)(b0 + (i + 2) * 64 + rT) * K2DIM + kp,
                    (void*)(smem + nb + (i + 2) * 4096 + dBase));
#pragma unroll
      for (int i = 0; i < 2; ++i)
        gload_lds16(srcB + (size_t)(g0 + i * 64 + rT) * N_DIM + kp,
                    (void*)(smem + nb + 16384 + i * 4096 + dBase));
    }
    LGKM(4); SB0();
    __builtin_amdgcn_s_setprio(1);
#pragma unroll
    for (int mi = 0; mi < 2; ++mi)
#pragma unroll
      for (int ni = 0; ni < 2; ++ni)
#pragma unroll
        for (int ks = 0; ks < 2; ++ks)
          acci[mi][ni] = __builtin_amdgcn_mfma_f32_32x32x16_bf16(aL[mi][ks], piB[ni][ks], acci[mi][ni], 0, 0, 0);
    __builtin_amdgcn_s_setprio(0);

    // ---- P2: prN = -prB; S2: accr += aH*pi
#pragma unroll
    for (int ni = 0; ni < 2; ++ni)
#pragma unroll
      for (int ks = 0; ks < 2; ++ks)
        prN[ni][ks] = negbf(prB[ni][ks]);
    LGKM(0); SB0();
    __builtin_amdgcn_s_setprio(1);
#pragma unroll
    for (int mi = 0; mi < 2; ++mi)
#pragma unroll
      for (int ni = 0; ni < 2; ++ni)
#pragma unroll
        for (int ks = 0; ks < 2; ++ks)
          accr[mi][ni] = __builtin_amdgcn_mfma_f32_32x32x16_bf16(aH[mi][ks], piB[ni][ks], accr[mi][ni], 0, 0, 0);
    __builtin_amdgcn_s_setprio(0);

    // ---- P3: tile boundary; pre-read next aL+prB; S3: acci += aH*(-pr)
    if (pf) {
      asm volatile("s_waitcnt vmcnt(0)" ::: "memory");
      __builtin_amdgcn_s_barrier();
      const ushort_t* bn = smem + nb;
#pragma unroll
      for (int mi = 0; mi < 2; ++mi)
#pragma unroll
        for (int ks = 0; ks < 2; ++ks)
          aL[mi][ks] = *(const bf16x8*)&bn[rowA[mi] + colL[ks]];
#pragma unroll
      for (int ni = 0; ni < 2; ++ni)
#pragma unroll
        for (int ks = 0; ks < 2; ++ks)
          prB[ni][ks] = *(const bf16x8*)&bn[rowB[ni] + colL[ks]];
      SB0();
    }
    __builtin_amdgcn_s_setprio(1);
#pragma unroll
    for (int mi = 0; mi < 2; ++mi)
#pragma unroll
      for (int ni = 0; ni < 2; ++ni)
#pragma unroll
        for (int ks = 0; ks < 2; ++ks)
          acci[mi][ni] = __builtin_amdgcn_mfma_f32_32x32x16_bf16(aH[mi][ks], prN[ni][ks], acci[mi][ni], 0, 0, 0);
    __builtin_amdgcn_s_setprio(0);
  }

  // epilogue: |x|^2 as bf16. C/D: col=l&31, row=(reg&3)+8*(reg>>2)+4*(l>>5)
  const int rb0 = wm * 64 + 4 * (l >> 5);
#pragma unroll
  for (int mi = 0; mi < 2; ++mi)
#pragma unroll
    for (int ni = 0; ni < 2; ++ni) {
      const int gcol = g0 + wn * 64 + ni * 32 + (l & 31);
      const f32x16 r = accr[mi][ni], q = acci[mi][ni];
#pragma unroll
      for (int reg = 0; reg < 16; ++reg) {
        const int row = rb0 + mi * 32 + (reg & 3) + 8 * (reg >> 2);
        xabsBf[(size_t)(b0 + row) * G_DIM + gcol] = f2bf(r[reg] * r[reg] + q[reg] * q[reg]);
      }
    }
}

// ---------- K3: fused scan + fp64 refine + y + scatter (+zero if fallback) --
// mode=1 (big/ws-psi): x planes pre-zeroed by k_gemm -> scatter both only.
// mode=0 (fallback): zero+scatter imag here; k_fin zeroes+scatters real.
__global__ __launch_bounds__(256) void k_sry(
    const ushort_t* __restrict__ xb, const float* __restrict__ H,
    const float* __restrict__ prT, const float* __restrict__ piT,
    int* __restrict__ wg, float* __restrict__ wxr, float* __restrict__ wxi,
    float* __restrict__ out, const int mode) {
  __shared__ float red[4];
  __shared__ int scnt;
  __shared__ int scand[64];
  __shared__ double dred[8];
  __shared__ int sbg;
  __shared__ float sxr, sxi;
  const int b = blockIdx.x, tid = threadIdx.x;
  const int l = tid & 63, w = tid >> 6;
  // ---- scan phase: bf16 row (8KB), block max, candidates within 0.25
  const ushort_t* row = xb + (size_t)b * G_DIM + tid * 16;
  const u16x8 u0 = *(const u16x8*)row;
  const u16x8 u1 = *(const u16x8*)(row + 8);
  float v[16];
#pragma unroll
  for (int j = 0; j < 8; ++j) { v[j] = bf2f(u0[j]); v[8 + j] = bf2f(u1[j]); }
  float m = v[0];
#pragma unroll
  for (int j = 1; j < 16; ++j) m = fmaxf(m, v[j]);
#pragma unroll
  for (int off = 32; off; off >>= 1) m = fmaxf(m, __shfl_xor(m, off));
  if (tid == 0) scnt = 0;
  if (l == 0) red[w] = m;
  __syncthreads();
  const float thr = fmaxf(fmaxf(red[0], red[1]), fmaxf(red[2], red[3])) - 0.25f;
#pragma unroll
  for (int j = 0; j < 16; ++j)
    if (v[j] >= thr) { int p = atomicAdd(&scnt, 1); if (p < 64) scand[p] = tid * 16 + j; }
  __syncthreads();
  int cnt = scnt;
  if (cnt > 64) cnt = 64;
  // ---- refine phase: hoisted H (each thread owns n = tid*4 .. tid*4+3)
  const int n0 = tid * 4;
  const float4 hr4 = *reinterpret_cast<const float4*>(H + (size_t)b * N_DIM + n0);
  const float4 hi4 = *reinterpret_cast<const float4*>(H + (size_t)B_DIM * N_DIM + (size_t)b * N_DIM + n0);
  double best = -1.0, bxr = 0.0, bxi = 0.0;
  int bg = 0;
  for (int ci = 0; ci < cnt; ++ci) {
    const int g = scand[ci];
    const float4 p4 = *reinterpret_cast<const float4*>(prT + (size_t)g * N_DIM + n0);
    const float4 q4 = *reinterpret_cast<const float4*>(piT + (size_t)g * N_DIM + n0);
    double xr = (double)hr4.x * p4.x - (double)hi4.x * q4.x;
    double xi = (double)hr4.x * q4.x + (double)hi4.x * p4.x;
    xr += (double)hr4.y * p4.y - (double)hi4.y * q4.y;
    xi += (double)hr4.y * q4.y + (double)hi4.y * p4.y;
    xr += (double)hr4.z * p4.z - (double)hi4.z * q4.z;
    xi += (double)hr4.z * q4.z + (double)hi4.z * p4.z;
    xr += (double)hr4.w * p4.w - (double)hi4.w * q4.w;
    xi += (double)hr4.w * q4.w + (double)hi4.w * p4.w;
    for (int off = 32; off; off >>= 1) {
      xr += __shfl_down(xr, off);
      xi += __shfl_down(xi, off);
    }
    if (l == 0) { dred[w * 2] = xr; dred[w * 2 + 1] = xi; }
    __syncthreads();
    if (tid == 0) {
      const double sxrr = dred[0] + dred[2] + dred[4] + dred[6];
      const double sxii = dred[1] + dred[3] + dred[5] + dred[7];
      const double xab = sxrr * sxrr + sxii * sxii;
      if (xab > best || (xab == best && g < bg)) { best = xab; bg = g; bxr = sxrr; bxi = sxii; }
    }
    __syncthreads();
  }
  if (tid == 0) {
    wg[b] = bg; wxr[b] = (float)bxr; wxi[b] = (float)bxi;
    sbg = bg; sxr = (float)bxr; sxi = (float)bxi;
  }
  __syncthreads();
  // ---- y phase (f32 psi, winner column)
  const int g = sbg;
  const float xr = sxr, xi = sxi;
  const float4 p4 = *reinterpret_cast<const float4*>(prT + (size_t)g * N_DIM + n0);
  const float4 q4 = *reinterpret_cast<const float4*>(piT + (size_t)g * N_DIM + n0);
  float4 vr, vi;
  vr.x = xr * p4.x + xi * q4.x; vi.x = xi * p4.x - xr * q4.x;
  vr.y = xr * p4.y + xi * q4.y; vi.y = xi * p4.y - xr * q4.y;
  vr.z = xr * p4.z + xi * q4.z; vi.z = xi * p4.z - xr * q4.z;
  vr.w = xr * p4.w + xi * q4.w; vi.w = xi * p4.w - xr * q4.w;
  float* yr = out + (size_t)2 * B_DIM * G_DIM + (size_t)b * N_DIM;
  float* yi = yr + (size_t)B_DIM * N_DIM;
  *reinterpret_cast<float4*>(yr + n0) = vr;
  *reinterpret_cast<float4*>(yi + n0) = vi;
  if (mode == 0) {
    // fallback: zero x-imag row b here
    const float4 z = {0.f, 0.f, 0.f, 0.f};
    float* zi = out + (size_t)B_DIM * G_DIM + (size_t)b * G_DIM + tid * 16;
#pragma unroll
    for (int j = 0; j < 4; ++j) *reinterpret_cast<float4*>(zi + j * 4) = z;
  }
  __syncthreads();
  if (tid == 0) {
    out[(size_t)B_DIM * G_DIM + (size_t)b * G_DIM + g] = xi;
    if (mode == 1) out[(size_t)b * G_DIM + g] = xr;  // real pre-zeroed by gemm
  }
}

// ---------- K4 (fallback only): zero x-real plane + real scatter ----------
__global__ __launch_bounds__(256) void k_fin(const int* __restrict__ wg,
                                             const float* __restrict__ wxr,
                                             float* __restrict__ out) {
  const int b = blockIdx.x, tid = threadIdx.x;
  const float4 z = {0.f, 0.f, 0.f, 0.f};
  float* zr = out + (size_t)b * G_DIM + tid * 16;
#pragma unroll
  for (int j = 0; j < 4; ++j) *reinterpret_cast<float4*>(zr + j * 4) = z;
  __syncthreads();
  if (tid == 0) out[(size_t)b * G_DIM + wg[b]] = wxr[b];
}

extern "C" void kernel_launch(void* const* d_in, const int* in_sizes, int n_in,
                              void* d_out, int out_size, void* d_ws, size_t ws_size,
                              hipStream_t stream) {
  const float* H = (const float*)d_in[0];
  const float* theta = (const float*)d_in[1];
  const float* alpha = (const float*)d_in[2];
  float* out = (float*)d_out;
  char* ws = (char*)d_ws;

  ushort_t* prBf = (ushort_t*)(ws + WS_PRBF);
  ushort_t* piBf = (ushort_t*)(ws + WS_PIBF);
  ushort_t* hbf = (ushort_t*)(ws + WS_HBF);
  ushort_t* xabsBf = (ushort_t*)(ws + WS_XABS);
  int* wg = (int*)(ws + WS_WG);
  float* wxr = (float*)(ws + WS_WXR);
  float* wxi = (float*)(ws + WS_WXI);

  // psi f32 scratch: ws if it fits (x planes stay clean -> gemm zeroes them),
  // else the out x-real plane (fallback path, k_fin zeroes real at the end).
  const bool big = ws_size >= (size_t)WS_BIG;
  float* prT = big ? (float*)(ws + WS_PRT) : out;
  float* piT = big ? (float*)(ws + WS_PIT) : out + 4194304;

  k_prep<<<8192, 256, 0, stream>>>(theta, alpha, H, prT, piT, prBf, piBf, hbf);
  k_gemm<<<256, 512, 0, stream>>>(hbf, prBf, piBf, xabsBf, out, big ? 1 : 0);
  k_sry<<<B_DIM, 256, 0, stream>>>(xabsBf, H, prT, piT, wg, wxr, wxi, out, big ? 1 : 0);
  if (!big) k_fin<<<B_DIM, 256, 0, stream>>>(wg, wxr, out);
}

// Round 19
// 101.362 us; speedup vs baseline: 1.2690x; 1.0014x over previous
//
#include <hip/hip_runtime.h>
#include <math.h>

#define N_DIM 1024
#define G_DIM 4096
#define B_DIM 2048
#define K2DIM 2048  // 2*N (real|imag concatenated K)

typedef __attribute__((ext_vector_type(8))) short bf16x8;
typedef __attribute__((ext_vector_type(8))) unsigned short u16x8;
typedef __attribute__((ext_vector_type(16))) float f32x16;
typedef unsigned short ushort_t;

// ---------- ws layout (bytes) ----------
#define WS_PRBF  0u                      // bf16 [G][1024]   8 MB
#define WS_PIBF  (8u << 20)              // bf16 [G][1024]   8 MB
#define WS_HBF   (16u << 20)             // bf16 [B][2048]   8 MB ([Hr | -Hi])
#define WS_XABS  (24u << 20)             // bf16 [B][G]     16 MB
#define WS_WG    (40u << 20)             // int [B]
#define WS_WXR   (WS_WG + 8192u)         // f32 [B]
#define WS_WXI   (WS_WXR + 8192u)        // f32 [B]
#define WS_PRT   (41u << 20)             // f32 [G][1024]  16 MB (optional)
#define WS_PIT   (57u << 20)             // f32 [G][1024]  16 MB (optional)
#define WS_BIG   (73u << 20)             // required ws_size for ws-psi path

__device__ __forceinline__ unsigned short f2bf(float f) {
  unsigned u = __float_as_uint(f);
  unsigned r = u + 0x7fffu + ((u >> 16) & 1u);
  return (unsigned short)(r >> 16);
}
__device__ __forceinline__ float bf2f(unsigned short u) {
  return __uint_as_float(((unsigned)u) << 16);
}
__device__ __forceinline__ bf16x8 negbf(bf16x8 v) {
  union { bf16x8 b; uint4 u; } x;
  x.b = v;
  x.u.x ^= 0x80008000u; x.u.y ^= 0x80008000u;
  x.u.z ^= 0x80008000u; x.u.w ^= 0x80008000u;
  return x.b;
}
// fast tanh via v_exp_f32 (alpha in [0,1) -> no overflow concerns)
__device__ __forceinline__ float tanh_fast(float x) {
  const float t = __expf(2.0f * x);
  return __fdividef(t - 1.0f, t + 1.0f);
}

__device__ __forceinline__ void gload_lds16(const void* gsrc, void* ldst) {
  __builtin_amdgcn_global_load_lds(
      (const __attribute__((address_space(1))) void*)gsrc,
      (__attribute__((address_space(3))) void*)ldst, 16, 0, 0);
}

// ---------- K1: fused PSI generation + H conversion (vectorized) ------
__global__ __launch_bounds__(256) void k_prep(
    const float* __restrict__ theta, const float* __restrict__ alpha,
    const float* __restrict__ H,
    float* __restrict__ prT, float* __restrict__ piT,
    ushort_t* __restrict__ prBf, ushort_t* __restrict__ piBf,
    ushort_t* __restrict__ hbf) {
  __shared__ float sp[32][33], si[32][33];
  const int bid = blockIdx.x, tid = threadIdx.x;
  if (bid < 4096) {
    // PSI: 32n x 32g tile; float4 reads, one pass (8 thr/row x 32 rows)
    const int g0 = (bid & 127) * 32, n0 = (bid >> 7) * 32;
    const int c4 = (tid & 7) * 4, row = tid >> 3;
    const size_t idx = (size_t)(n0 + row) * G_DIM + g0 + c4;
    const float4 a4 = *reinterpret_cast<const float4*>(alpha + idx);
    const float4 t4 = *reinterpret_cast<const float4*>(theta + idx);
#pragma unroll
    for (int j = 0; j < 4; ++j) {
      const float av = (j == 0) ? a4.x : (j == 1) ? a4.y : (j == 2) ? a4.z : a4.w;
      const float tv = (j == 0) ? t4.x : (j == 1) ? t4.y : (j == 2) ? t4.z : t4.w;
      const float a = tanh_fast(av) * 0.03125f;  // 1/sqrt(1024)
      sp[row][c4 + j] = a * __cosf(tv);
      si[row][c4 + j] = a * __sinf(tv);
    }
    __syncthreads();
    // write: g = g0 + row, n-quad = n0 + c4; float4 / ushort4 stores
    const size_t obase = (size_t)(g0 + row) * N_DIM + n0 + c4;
    float4 vr, vi;
    ushort4 ur, ui;
#pragma unroll
    for (int j = 0; j < 4; ++j) {
      const float pr = sp[c4 + j][row], pi = si[c4 + j][row];
      if (j == 0) { vr.x = pr; vi.x = pi; ur.x = f2bf(pr); ui.x = f2bf(pi); }
      else if (j == 1) { vr.y = pr; vi.y = pi; ur.y = f2bf(pr); ui.y = f2bf(pi); }
      else if (j == 2) { vr.z = pr; vi.z = pi; ur.z = f2bf(pr); ui.z = f2bf(pi); }
      else { vr.w = pr; vi.w = pi; ur.w = f2bf(pr); ui.w = f2bf(pi); }
    }
    *reinterpret_cast<float4*>(prT + obase) = vr;
    *reinterpret_cast<float4*>(piT + obase) = vi;
    *reinterpret_cast<ushort4*>(prBf + obase) = ur;
    *reinterpret_cast<ushort4*>(piBf + obase) = ui;
  } else {
    // H -> bf16, layout [B][2048] = [Hr | -Hi]
    const int j4 = ((bid - 4096) * 256 + tid) * 4;
    const int b = j4 >> 11, k = j4 & 2047, c = k >> 10, n = k & 1023;
    float4 v = *reinterpret_cast<const float4*>(
        H + (size_t)c * (B_DIM * N_DIM) + (size_t)b * N_DIM + n);
    if (c) { v.x = -v.x; v.y = -v.y; v.z = -v.z; v.w = -v.w; }
    ushort4 u;
    u.x = f2bf(v.x); u.y = f2bf(v.y); u.z = f2bf(v.z); u.w = f2bf(v.w);
    *reinterpret_cast<ushort4*>(hbf + j4) = u;
  }
}

#define LGKM(n) asm volatile("s_waitcnt lgkmcnt(" #n ")" ::: "memory")
#define SB0() __builtin_amdgcn_sched_barrier(0)

// ---------- K2: merged-B 32x32x16 dual-acc GEMM -> |x|^2 (bf16) ----------
// Best-measured core (62.8us): BM=256, BN=128, merged 32 k-lo + 32 k-hi.
// 8 waves 4M x 2N. LDS 2-ring x 48KB = 96KB; slot ^= row&7.
// accr = aL*pr + aH*pi ; acci = aL*pi + aH*(-pr)   (aH = -Hi)
// zeroX: zero this block's disjoint 256x128 slice of BOTH x-planes.
// Store issued in P2 (AFTER the 6 staging loads) so the P3 boundary wait
// can be vmcnt(1): drains the loads + previous store, leaves this store
// in flight with a full tile to retire (store-ack off the critical path).
__global__ __launch_bounds__(512, 2) void k_gemm(
    const ushort_t* __restrict__ hbf, const ushort_t* __restrict__ prBf,
    const ushort_t* __restrict__ piBf, ushort_t* __restrict__ xabsBf,
    float* __restrict__ xout, const int zeroX) {
  __shared__ ushort_t smem[49152];     // 96 KB: 2 bufs x 24576 ushorts
  const int tid = threadIdx.x;
  const int l = tid & 63, w = tid >> 6;
  const int wm = w >> 1, wn = w & 1;   // 4M x 2N
  const int bid = blockIdx.x;
  const int xcd = bid & 7, idx = bid >> 3;
  const int g0 = (xcd * 4 + (idx & 3)) * 128;
  const int b0 = (idx >> 2) * 256;

  // fragment offsets: rows 64 ushorts (128 B), slot ^= row&7 (row&7 == l&7)
  const int h = l >> 5;
  int colL[2], colH[2];
#pragma unroll
  for (int ks = 0; ks < 2; ++ks) {
    colL[ks] = ((ks * 2 + h) ^ (l & 7)) * 8;
    colH[ks] = ((4 + ks * 2 + h) ^ (l & 7)) * 8;
  }
  int rowA[2], rowB[2];
#pragma unroll
  for (int mi = 0; mi < 2; ++mi) rowA[mi] = (wm * 64 + mi * 32 + (l & 31)) * 64;
#pragma unroll
  for (int ni = 0; ni < 2; ++ni) rowB[ni] = 16384 + (wn * 64 + ni * 32 + (l & 31)) * 64;

  // staging: linear LDS dest, inverse-swizzled global source
  const int rT = tid >> 3, sd = tid & 7, sl = sd ^ (rT & 7);
  const ushort_t* srcA = hbf + (sl < 4 ? sl * 8 : 1024 + (sl - 4) * 8);
  const ushort_t* srcB = (sl < 4) ? (prBf + sl * 8) : (piBf + (sl - 4) * 8);
  const int dBase = (tid & ~63) * 8;

  // x-plane zero-store base for this thread (pass p covers rows b0+p*16..+15)
  float* xz0 = xout + (size_t)(b0 + (tid >> 5)) * G_DIM + g0 + (tid & 31) * 4;

  f32x16 accr[2][2], acci[2][2];
#pragma unroll
  for (int mi = 0; mi < 2; ++mi)
#pragma unroll
    for (int ni = 0; ni < 2; ++ni) {
      accr[mi][ni] = (f32x16)(0.f);
      acci[mi][ni] = (f32x16)(0.f);
    }

  // prologue: stage tile 0 into buf 0
#pragma unroll
  for (int i = 0; i < 4; ++i)
    gload_lds16(srcA + (size_t)(b0 + i * 64 + rT) * K2DIM, (void*)(smem + i * 4096 + dBase));
#pragma unroll
  for (int i = 0; i < 2; ++i)
    gload_lds16(srcB + (size_t)(g0 + i * 64 + rT) * N_DIM, (void*)(smem + 16384 + i * 4096 + dBase));
  asm volatile("s_waitcnt vmcnt(0)" ::: "memory");
  __builtin_amdgcn_s_barrier();

  bf16x8 aL[2][2], aH[2][2], prB[2][2], piB[2][2], prN[2][2];

  // pre-read aL + prB of tile 0 (8 reads outstanding entering the loop)
  {
    const ushort_t* buf = smem;
#pragma unroll
    for (int mi = 0; mi < 2; ++mi)
#pragma unroll
      for (int ks = 0; ks < 2; ++ks)
        aL[mi][ks] = *(const bf16x8*)&buf[rowA[mi] + colL[ks]];
#pragma unroll
    for (int ni = 0; ni < 2; ++ni)
#pragma unroll
      for (int ks = 0; ks < 2; ++ks)
        prB[ni][ks] = *(const bf16x8*)&buf[rowB[ni] + colL[ks]];
  }

  for (int t = 0; t < 32; ++t) {
    const ushort_t* buf = smem + (t & 1) * 24576;
    const int nb = ((t + 1) & 1) * 24576;
    const int kp = (t + 1) * 32;
    const bool pf = (t < 31);

    // ---- P0: read piB; stage A(0,1); S0: accr += aL*pr
#pragma unroll
    for (int ni = 0; ni < 2; ++ni)
#pragma unroll
      for (int ks = 0; ks < 2; ++ks)
        piB[ni][ks] = *(const bf16x8*)&buf[rowB[ni] + colH[ks]];
    if (pf) {
#pragma unroll
      for (int i = 0; i < 2; ++i)
        gload_lds16(srcA + (size_t)(b0 + i * 64 + rT) * K2DIM + kp,
                    (void*)(smem + nb + i * 4096 + dBase));
    }
    LGKM(4); SB0();
    __builtin_amdgcn_s_setprio(1);
#pragma unroll
    for (int mi = 0; mi < 2; ++mi)
#pragma unroll
      for (int ni = 0; ni < 2; ++ni)
#pragma unroll
        for (int ks = 0; ks < 2; ++ks)
          accr[mi][ni] = __builtin_amdgcn_mfma_f32_32x32x16_bf16(aL[mi][ks], prB[ni][ks], accr[mi][ni], 0, 0, 0);
    __builtin_amdgcn_s_setprio(0);

    // ---- P1: read aH; stage A(2,3) + B(0,1); S1: acci += aL*pi
#pragma unroll
    for (int mi = 0; mi < 2; ++mi)
#pragma unroll
      for (int ks = 0; ks < 2; ++ks)
        aH[mi][ks] = *(const bf16x8*)&buf[rowA[mi] + colH[ks]];
    if (pf) {
#pragma unroll
      for (int i = 0; i < 2; ++i)
        gload_lds16(srcA + (size_t)(b0 + (i + 2) * 64 + rT) * K2DIM + kp,
                    (void*)(smem + nb + (i + 2) * 4096 + dBase));
#pragma unroll
      for (int i = 0; i < 2; ++i)
        gload_lds16(srcB + (size_t)(g0 + i * 64 + rT) * N_DIM + kp,
                    (void*)(smem + nb + 16384 + i * 4096 + dBase));
    }
    LGKM(4); SB0();
    __builtin_amdgcn_s_setprio(1);
#pragma unroll
    for (int mi = 0; mi < 2; ++mi)
#pragma unroll
      for (int ni = 0; ni < 2; ++ni)
#pragma unroll
        for (int ks = 0; ks < 2; ++ks)
          acci[mi][ni] = __builtin_amdgcn_mfma_f32_32x32x16_bf16(aL[mi][ks], piB[ni][ks], acci[mi][ni], 0, 0, 0);
    __builtin_amdgcn_s_setprio(0);

    // ---- P2: prN = -prB; zero-store (AFTER staging loads); S2: accr += aH*pi
#pragma unroll
    for (int ni = 0; ni < 2; ++ni)
#pragma unroll
      for (int ks = 0; ks < 2; ++ks)
        prN[ni][ks] = negbf(prB[ni][ks]);
    if (zeroX) {
      // tile t: pass t&15 of plane (t<16 ? real : imag)
      float* xz = xz0 + (size_t)(t & 15) * 16 * G_DIM
                + (t < 16 ? 0 : (size_t)B_DIM * G_DIM);
      *reinterpret_cast<float4*>(xz) = (float4){0.f, 0.f, 0.f, 0.f};
    }
    LGKM(0); SB0();
    __builtin_amdgcn_s_setprio(1);
#pragma unroll
    for (int mi = 0; mi < 2; ++mi)
#pragma unroll
      for (int ni = 0; ni < 2; ++ni)
#pragma unroll
        for (int ks = 0; ks < 2; ++ks)
          accr[mi][ni] = __builtin_amdgcn_mfma_f32_32x32x16_bf16(aH[mi][ks], piB[ni][ks], accr[mi][ni], 0, 0, 0);
    __builtin_amdgcn_s_setprio(0);

    // ---- P3: boundary wait (vmcnt(1) leaves this tile's store in flight);
    //          barrier; pre-read next aL+prB; S3: acci += aH*(-pr)
    if (pf) {
      if (zeroX) {
        asm volatile("s_waitcnt vmcnt(1)" ::: "memory");
      } else {
        asm volatile("s_waitcnt vmcnt(0)" ::: "memory");
      }
      __builtin_amdgcn_s_barrier();
      const ushort_t* bn = smem + nb;
#pragma unroll
      for (int mi = 0; mi < 2; ++mi)
#pragma unroll
        for (int ks = 0; ks < 2; ++ks)
          aL[mi][ks] = *(const bf16x8*)&bn[rowA[mi] + colL[ks]];
#pragma unroll
      for (int ni = 0; ni < 2; ++ni)
#pragma unroll
        for (int ks = 0; ks < 2; ++ks)
          prB[ni][ks] = *(const bf16x8*)&bn[rowB[ni] + colL[ks]];
      SB0();
    }
    __builtin_amdgcn_s_setprio(1);
#pragma unroll
    for (int mi = 0; mi < 2; ++mi)
#pragma unroll
      for (int ni = 0; ni < 2; ++ni)
#pragma unroll
        for (int ks = 0; ks < 2; ++ks)
          acci[mi][ni] = __builtin_amdgcn_mfma_f32_32x32x16_bf16(aH[mi][ks], prN[ni][ks], acci[mi][ni], 0, 0, 0);
    __builtin_amdgcn_s_setprio(0);
  }

  // epilogue: |x|^2 as bf16. C/D: col=l&31, row=(reg&3)+8*(reg>>2)+4*(l>>5)
  const int rb0 = wm * 64 + 4 * (l >> 5);
#pragma unroll
  for (int mi = 0; mi < 2; ++mi)
#pragma unroll
    for (int ni = 0; ni < 2; ++ni) {
      const int gcol = g0 + wn * 64 + ni * 32 + (l & 31);
      const f32x16 r = accr[mi][ni], q = acci[mi][ni];
#pragma unroll
      for (int reg = 0; reg < 16; ++reg) {
        const int row = rb0 + mi * 32 + (reg & 3) + 8 * (reg >> 2);
        xabsBf[(size_t)(b0 + row) * G_DIM + gcol] = f2bf(r[reg] * r[reg] + q[reg] * q[reg]);
      }
    }
}

// ---------- K3: fused scan + fp64 refine + y + scatter (+zero if fallback) --
// mode=1 (big/ws-psi): x planes pre-zeroed by k_gemm -> scatter both only.
// mode=0 (fallback): zero+scatter imag here; k_fin zeroes+scatters real.
__global__ __launch_bounds__(256) void k_sry(
    const ushort_t* __restrict__ xb, const float* __restrict__ H,
    const float* __restrict__ prT, const float* __restrict__ piT,
    int* __restrict__ wg, float* __restrict__ wxr, float* __restrict__ wxi,
    float* __restrict__ out, const int mode) {
  __shared__ float red[4];
  __shared__ int scnt;
  __shared__ int scand[64];
  __shared__ double dred[8];
  __shared__ int sbg;
  __shared__ float sxr, sxi;
  const int b = blockIdx.x, tid = threadIdx.x;
  const int l = tid & 63, w = tid >> 6;
  // ---- scan phase: bf16 row (8KB), block max, candidates within 0.25
  const ushort_t* row = xb + (size_t)b * G_DIM + tid * 16;
  const u16x8 u0 = *(const u16x8*)row;
  const u16x8 u1 = *(const u16x8*)(row + 8);
  float v[16];
#pragma unroll
  for (int j = 0; j < 8; ++j) { v[j] = bf2f(u0[j]); v[8 + j] = bf2f(u1[j]); }
  float m = v[0];
#pragma unroll
  for (int j = 1; j < 16; ++j) m = fmaxf(m, v[j]);
#pragma unroll
  for (int off = 32; off; off >>= 1) m = fmaxf(m, __shfl_xor(m, off));
  if (tid == 0) scnt = 0;
  if (l == 0) red[w] = m;
  __syncthreads();
  const float thr = fmaxf(fmaxf(red[0], red[1]), fmaxf(red[2], red[3])) - 0.25f;
#pragma unroll
  for (int j = 0; j < 16; ++j)
    if (v[j] >= thr) { int p = atomicAdd(&scnt, 1); if (p < 64) scand[p] = tid * 16 + j; }
  __syncthreads();
  int cnt = scnt;
  if (cnt > 64) cnt = 64;
  // ---- refine phase: hoisted H (each thread owns n = tid*4 .. tid*4+3)
  const int n0 = tid * 4;
  const float4 hr4 = *reinterpret_cast<const float4*>(H + (size_t)b * N_DIM + n0);
  const float4 hi4 = *reinterpret_cast<const float4*>(H + (size_t)B_DIM * N_DIM + (size_t)b * N_DIM + n0);
  double best = -1.0, bxr = 0.0, bxi = 0.0;
  int bg = 0;
  for (int ci = 0; ci < cnt; ++ci) {
    const int g = scand[ci];
    const float4 p4 = *reinterpret_cast<const float4*>(prT + (size_t)g * N_DIM + n0);
    const float4 q4 = *reinterpret_cast<const float4*>(piT + (size_t)g * N_DIM + n0);
    double xr = (double)hr4.x * p4.x - (double)hi4.x * q4.x;
    double xi = (double)hr4.x * q4.x + (double)hi4.x * p4.x;
    xr += (double)hr4.y * p4.y - (double)hi4.y * q4.y;
    xi += (double)hr4.y * q4.y + (double)hi4.y * p4.y;
    xr += (double)hr4.z * p4.z - (double)hi4.z * q4.z;
    xi += (double)hr4.z * q4.z + (double)hi4.z * p4.z;
    xr += (double)hr4.w * p4.w - (double)hi4.w * q4.w;
    xi += (double)hr4.w * q4.w + (double)hi4.w * p4.w;
    for (int off = 32; off; off >>= 1) {
      xr += __shfl_down(xr, off);
      xi += __shfl_down(xi, off);
    }
    if (l == 0) { dred[w * 2] = xr; dred[w * 2 + 1] = xi; }
    __syncthreads();
    if (tid == 0) {
      const double sxrr = dred[0] + dred[2] + dred[4] + dred[6];
      const double sxii = dred[1] + dred[3] + dred[5] + dred[7];
      const double xab = sxrr * sxrr + sxii * sxii;
      if (xab > best || (xab == best && g < bg)) { best = xab; bg = g; bxr = sxrr; bxi = sxii; }
    }
    __syncthreads();
  }
  if (tid == 0) {
    wg[b] = bg; wxr[b] = (float)bxr; wxi[b] = (float)bxi;
    sbg = bg; sxr = (float)bxr; sxi = (float)bxi;
  }
  __syncthreads();
  // ---- y phase (f32 psi, winner column)
  const int g = sbg;
  const float xr = sxr, xi = sxi;
  const float4 p4 = *reinterpret_cast<const float4*>(prT + (size_t)g * N_DIM + n0);
  const float4 q4 = *reinterpret_cast<const float4*>(piT + (size_t)g * N_DIM + n0);
  float4 vr, vi;
  vr.x = xr * p4.x + xi * q4.x; vi.x = xi * p4.x - xr * q4.x;
  vr.y = xr * p4.y + xi * q4.y; vi.y = xi * p4.y - xr * q4.y;
  vr.z = xr * p4.z + xi * q4.z; vi.z = xi * p4.z - xr * q4.z;
  vr.w = xr * p4.w + xi * q4.w; vi.w = xi * p4.w - xr * q4.w;
  float* yr = out + (size_t)2 * B_DIM * G_DIM + (size_t)b * N_DIM;
  float* yi = yr + (size_t)B_DIM * N_DIM;
  *reinterpret_cast<float4*>(yr + n0) = vr;
  *reinterpret_cast<float4*>(yi + n0) = vi;
  if (mode == 0) {
    // fallback: zero x-imag row b here
    const float4 z = {0.f, 0.f, 0.f, 0.f};
    float* zi = out + (size_t)B_DIM * G_DIM + (size_t)b * G_DIM + tid * 16;
#pragma unroll
    for (int j = 0; j < 4; ++j) *reinterpret_cast<float4*>(zi + j * 4) = z;
  }
  __syncthreads();
  if (tid == 0) {
    out[(size_t)B_DIM * G_DIM + (size_t)b * G_DIM + g] = xi;
    if (mode == 1) out[(size_t)b * G_DIM + g] = xr;  // real pre-zeroed by gemm
  }
}

// ---------- K4 (fallback only): zero x-real plane + real scatter ----------
__global__ __launch_bounds__(256) void k_fin(const int* __restrict__ wg,
                                             const float* __restrict__ wxr,
                                             float* __restrict__ out) {
  const int b = blockIdx.x, tid = threadIdx.x;
  const float4 z = {0.f, 0.f, 0.f, 0.f};
  float* zr = out + (size_t)b * G_DIM + tid * 16;
#pragma unroll
  for (int j = 0; j < 4; ++j) *reinterpret_cast<float4*>(zr + j * 4) = z;
  __syncthreads();
  if (tid == 0) out[(size_t)b * G_DIM + wg[b]] = wxr[b];
}

extern "C" void kernel_launch(void* const* d_in, const int* in_sizes, int n_in,
                              void* d_out, int out_size, void* d_ws, size_t ws_size,
                              hipStream_t stream) {
  const float* H = (const float*)d_in[0];
  const float* theta = (const float*)d_in[1];
  const float* alpha = (const float*)d_in[2];
  float* out = (float*)d_out;
  char* ws = (char*)d_ws;

  ushort_t* prBf = (ushort_t*)(ws + WS_PRBF);
  ushort_t* piBf = (ushort_t*)(ws + WS_PIBF);
  ushort_t* hbf = (ushort_t*)(ws + WS_HBF);
  ushort_t* xabsBf = (ushort_t*)(ws + WS_XABS);
  int* wg = (int*)(ws + WS_WG);
  float* wxr = (float*)(ws + WS_WXR);
  float* wxi = (float*)(ws + WS_WXI);

  // psi f32 scratch: ws if it fits (x planes stay clean -> gemm zeroes them),
  // else the out x-real plane (fallback path, k_fin zeroes real at the end).
  const bool big = ws_size >= (size_t)WS_BIG;
  float* prT = big ? (float*)(ws + WS_PRT) : out;
  float* piT = big ? (float*)(ws + WS_PIT) : out + 4194304;

  k_prep<<<8192, 256, 0, stream>>>(theta, alpha, H, prT, piT, prBf, piBf, hbf);
  k_gemm<<<256, 512, 0, stream>>>(hbf, prBf, piBf, xabsBf, out, big ? 1 : 0);
  k_sry<<<B_DIM, 256, 0, stream>>>(xabsBf, H, prT, piT, wg, wxr, wxi, out, big ? 1 : 0);
  if (!big) k_fin<<<B_DIM, 256, 0, stream>>>(wg, wxr, out);
}